// Round 1
// baseline (1873.764 us; speedup 1.0000x reference)
//
#include <hip/hip_runtime.h>
#include <hip/hip_bf16.h>
#include <stdint.h>

#define HD 64

__device__ __forceinline__ void atomAddF(float* p, float v) {
    unsafeAtomicAdd(p, v);   // hw global_atomic_add_f32 / ds_add_f32 on gfx950
}

// xm[m][j] = sum_f movie_x[m][f] * W[f][j] + b[j] + movie_emb[mid[m]][j]
__global__ __launch_bounds__(256) void k_movie_feat(
    const float* __restrict__ mx, const float* __restrict__ W,
    const float* __restrict__ b, const float* __restrict__ memb,
    const int* __restrict__ mids, float* __restrict__ xm, int NM, int F)
{
    int m = blockIdx.x * blockDim.x + threadIdx.x;
    if (m >= NM) return;
    const float* xr = mx + (size_t)m * F;
    float acc[HD];
    #pragma unroll
    for (int j = 0; j < HD; ++j) acc[j] = b[j];
    for (int f = 0; f < F; ++f) {
        float v = xr[f];
        #pragma unroll
        for (int j = 0; j < HD; ++j) acc[j] += v * W[f * HD + j];
    }
    int nid = mids[m];
    const float* er = memb + (size_t)nid * HD;
    float4* o = (float4*)(xm + (size_t)m * HD);
    #pragma unroll
    for (int j = 0; j < HD; j += 4) {
        float4 e = *(const float4*)(er + j);
        o[j >> 2] = make_float4(acc[j] + e.x, acc[j + 1] + e.y, acc[j + 2] + e.z, acc[j + 3] + e.w);
    }
}

// dst[i][h] = src[idx[i]][h]
__global__ __launch_bounds__(256) void k_gather_rows(
    const float* __restrict__ src, const int* __restrict__ idx,
    float* __restrict__ dst, int N)
{
    int t = blockIdx.x * blockDim.x + threadIdx.x;
    int total = N * HD;
    int stride = gridDim.x * blockDim.x;
    for (; t < total; t += stride) {
        int i = t >> 6, h = t & 63;
        dst[t] = src[(size_t)idx[i] * HD + h];
    }
}

// for each edge e: agg[dst[e]][h] += xsrc[src[e]][h]; cnt[dst[e]] += 1
__global__ __launch_bounds__(256) void k_scatter(
    const float* __restrict__ xsrc, const int* __restrict__ src,
    const int* __restrict__ dst, float* __restrict__ agg,
    float* __restrict__ cnt, int E)
{
    int group = threadIdx.x >> 6;
    int h = threadIdx.x & 63;
    int e = blockIdx.x * (blockDim.x >> 6) + group;
    if (e >= E) return;
    int s = src[e], d = dst[e];
    float v = xsrc[(size_t)s * HD + h];
    atomAddF(&agg[(size_t)d * HD + h], v);
    if (h == 0) atomAddF(&cnt[d], 1.0f);
}

// out[n] = (agg[n]/max(cnt,1)) @ wl + bl + xdst[n] @ wr   (thread-per-node, scalar weights)
__global__ __launch_bounds__(256) void k_sage_linear(
    const float* __restrict__ agg, const float* __restrict__ cnt,
    const float* __restrict__ xdst,
    const float* __restrict__ wl, const float* __restrict__ blv,
    const float* __restrict__ wr,
    float* __restrict__ out, int N)
{
    int n = blockIdx.x * blockDim.x + threadIdx.x;
    if (n >= N) return;
    float c = cnt[n]; c = c > 1.f ? c : 1.f;
    float inv = 1.f / c;
    const float* ag = agg + (size_t)n * HD;
    const float* xd = xdst + (size_t)n * HD;
    float acc[HD];
    #pragma unroll
    for (int j = 0; j < HD; ++j) acc[j] = blv[j];
    for (int i = 0; i < HD; i += 4) {
        float4 m = *(const float4*)(ag + i);
        m.x *= inv; m.y *= inv; m.z *= inv; m.w *= inv;
        float4 x = *(const float4*)(xd + i);
        #pragma unroll
        for (int j = 0; j < HD; ++j) {
            acc[j] += m.x * wl[(i + 0) * HD + j] + m.y * wl[(i + 1) * HD + j]
                    + m.z * wl[(i + 2) * HD + j] + m.w * wl[(i + 3) * HD + j]
                    + x.x * wr[(i + 0) * HD + j] + x.y * wr[(i + 1) * HD + j]
                    + x.z * wr[(i + 2) * HD + j] + x.w * wr[(i + 3) * HD + j];
        }
    }
    float4* o = (float4*)(out + (size_t)n * HD);
    #pragma unroll
    for (int j = 0; j < HD; j += 4)
        o[j >> 2] = make_float4(acc[j], acc[j + 1], acc[j + 2], acc[j + 3]);
}

// column sums / sumsq of x[N][64] into stats[0..63]=sum, [64..127]=sumsq
__global__ __launch_bounds__(256) void k_colstats(
    const float* __restrict__ x, float* __restrict__ stats, int N)
{
    __shared__ float ssum[HD], ssq[HD];
    if (threadIdx.x < HD) { ssum[threadIdx.x] = 0.f; ssq[threadIdx.x] = 0.f; }
    __syncthreads();
    const float4* x4 = (const float4*)x;
    int total4 = N * (HD / 4);
    int t = blockIdx.x * blockDim.x + threadIdx.x;
    int stride = gridDim.x * blockDim.x;   // multiple of 16 -> h constant per thread
    int h = (t * 4) & 63;
    float s0 = 0, s1 = 0, s2 = 0, s3 = 0, q0 = 0, q1 = 0, q2 = 0, q3 = 0;
    for (; t < total4; t += stride) {
        float4 v = x4[t];
        s0 += v.x; q0 += v.x * v.x;
        s1 += v.y; q1 += v.y * v.y;
        s2 += v.z; q2 += v.z * v.z;
        s3 += v.w; q3 += v.w * v.w;
    }
    atomAddF(&ssum[h + 0], s0); atomAddF(&ssq[h + 0], q0);
    atomAddF(&ssum[h + 1], s1); atomAddF(&ssq[h + 1], q1);
    atomAddF(&ssum[h + 2], s2); atomAddF(&ssq[h + 2], q2);
    atomAddF(&ssum[h + 3], s3); atomAddF(&ssq[h + 3], q3);
    __syncthreads();
    if (threadIdx.x < HD) {
        atomAddF(&stats[threadIdx.x], ssum[threadIdx.x]);
        atomAddF(&stats[HD + threadIdx.x], ssq[threadIdx.x]);
    }
}

// ss[j] = g*rsqrt(var+eps); ss[64+j] = b - mu*ss[j]
__global__ void k_bn_finalize(const float* __restrict__ stats,
                              const float* __restrict__ g, const float* __restrict__ b,
                              float* __restrict__ ss, int N)
{
    int j = threadIdx.x;
    if (j < HD) {
        float invN = 1.f / (float)N;
        float mu = stats[j] * invN;
        float var = stats[HD + j] * invN - mu * mu;
        var = var < 0.f ? 0.f : var;
        float sc = g[j] * rsqrtf(var + 1e-5f);
        ss[j] = sc;
        ss[HD + j] = b[j] - mu * sc;
    }
}

__global__ __launch_bounds__(256) void k_bn_relu(
    float4* __restrict__ x, const float* __restrict__ ss, int total4)
{
    int t = blockIdx.x * blockDim.x + threadIdx.x;
    int stride = gridDim.x * blockDim.x;
    for (; t < total4; t += stride) {
        int h = (t * 4) & 63;
        float4 v = x[t];
        v.x = fmaxf(v.x * ss[h + 0] + ss[HD + h + 0], 0.f);
        v.y = fmaxf(v.y * ss[h + 1] + ss[HD + h + 1], 0.f);
        v.z = fmaxf(v.z * ss[h + 2] + ss[HD + h + 2], 0.f);
        v.w = fmaxf(v.w * ss[h + 3] + ss[HD + h + 3], 0.f);
        x[t] = v;
    }
}

// out[l] = relu(concat(xu[ls],xm[ld]) @ w1 + b1) @ w2 + b2   (thread-per-label)
__global__ __launch_bounds__(256) void k_classifier(
    const float* __restrict__ xu, const float* __restrict__ xm,
    const int* __restrict__ lsrc, const int* __restrict__ ldst,
    const float* __restrict__ w1, const float* __restrict__ b1,
    const float* __restrict__ w2, const float* __restrict__ b2,
    float* __restrict__ out, int L)
{
    int l = blockIdx.x * blockDim.x + threadIdx.x;
    if (l >= L) return;
    const float* ur = xu + (size_t)lsrc[l] * HD;
    const float* mr = xm + (size_t)ldst[l] * HD;
    float acc[HD];
    #pragma unroll
    for (int j = 0; j < HD; ++j) acc[j] = b1[j];
    for (int i = 0; i < HD; i += 4) {
        float4 a = *(const float4*)(ur + i);
        #pragma unroll
        for (int j = 0; j < HD; ++j)
            acc[j] += a.x * w1[(i + 0) * HD + j] + a.y * w1[(i + 1) * HD + j]
                    + a.z * w1[(i + 2) * HD + j] + a.w * w1[(i + 3) * HD + j];
    }
    for (int i = 0; i < HD; i += 4) {
        float4 a = *(const float4*)(mr + i);
        #pragma unroll
        for (int j = 0; j < HD; ++j)
            acc[j] += a.x * w1[(HD + i + 0) * HD + j] + a.y * w1[(HD + i + 1) * HD + j]
                    + a.z * w1[(HD + i + 2) * HD + j] + a.w * w1[(HD + i + 3) * HD + j];
    }
    float r = b2[0];
    #pragma unroll
    for (int j = 0; j < HD; ++j) r += fmaxf(acc[j], 0.f) * w2[j];
    out[l] = r;
}

extern "C" void kernel_launch(void* const* d_in, const int* in_sizes, int n_in,
                              void* d_out, int out_size, void* d_ws, size_t ws_size,
                              hipStream_t stream) {
    (void)n_in; (void)ws_size;
    const int NU = in_sizes[1] / HD;
    const int NM = in_sizes[2] / HD;
    const int F  = in_sizes[0] / NM;
    const int E  = in_sizes[31];
    const int L  = out_size;

    // resolve input ordering: setup-dict order (bn interleaved) vs signature order
    int iL0RA, iL0RE, iL1RA, iL1RE, iBN0U, iBN0M, iBN1U, iBN1M;
    if (in_sizes[11] == HD) {          // setup-dict order
        iL0RA = 5; iL0RE = 8; iBN0U = 11; iBN0M = 13;
        iL1RA = 15; iL1RE = 18; iBN1U = 21; iBN1M = 23;
    } else {                           // reference-signature order
        iL0RA = 5; iL0RE = 8; iL1RA = 11; iL1RE = 14;
        iBN0U = 17; iBN0M = 19; iBN1U = 21; iBN1M = 23;
    }
    const float* movie_x   = (const float*)d_in[0];
    const float* user_emb  = (const float*)d_in[1];
    const float* movie_emb = (const float*)d_in[2];
    const float* mlw       = (const float*)d_in[3];
    const float* mlb       = (const float*)d_in[4];
    const float* cls_w1    = (const float*)d_in[25];
    const float* cls_b1    = (const float*)d_in[26];
    const float* cls_w2    = (const float*)d_in[27];
    const float* cls_b2    = (const float*)d_in[28];
    const int* user_node_id  = (const int*)d_in[29];
    const int* movie_node_id = (const int*)d_in[30];
    const int* rates_src   = (const int*)d_in[31];
    const int* rates_dst   = (const int*)d_in[32];
    const int* label_src   = (const int*)d_in[33];
    const int* label_dst   = (const int*)d_in[34];

    // workspace layout (floats)
    float* ws  = (float*)d_ws;
    float* xu0 = ws;
    float* xu1 = xu0 + (size_t)NU * HD;
    float* xm0 = xu1 + (size_t)NU * HD;
    float* xm1 = xm0 + (size_t)NM * HD;
    float* agg = xm1 + (size_t)NM * HD;
    float* cnt = agg + (size_t)NU * HD;
    float* stats = cnt + NU;       // 128 floats
    float* ss    = stats + 2 * HD; // 128 floats

    // stage helper
    auto sage_stage = [&](const float* xsrc, const int* srcIdx, const int* dstIdx, int Ndst,
                          const float* xdst, int iW, int iBN, float* outBuf) {
        const float* wl = (const float*)d_in[iW + 0];
        const float* bl = (const float*)d_in[iW + 1];
        const float* wr = (const float*)d_in[iW + 2];
        const float* g  = (const float*)d_in[iBN + 0];
        const float* bb = (const float*)d_in[iBN + 1];
        hipMemsetAsync(agg, 0, (size_t)Ndst * HD * sizeof(float), stream);
        hipMemsetAsync(cnt, 0, (size_t)Ndst * sizeof(float), stream);
        hipMemsetAsync(stats, 0, 2 * HD * sizeof(float), stream);
        k_scatter<<<(E + 3) / 4, 256, 0, stream>>>(xsrc, srcIdx, dstIdx, agg, cnt, E);
        k_sage_linear<<<(Ndst + 255) / 256, 256, 0, stream>>>(agg, cnt, xdst, wl, bl, wr, outBuf, Ndst);
        k_colstats<<<1024, 256, 0, stream>>>(outBuf, stats, Ndst);
        k_bn_finalize<<<1, 64, 0, stream>>>(stats, g, bb, ss, Ndst);
        k_bn_relu<<<1024, 256, 0, stream>>>((float4*)outBuf, ss, Ndst * (HD / 4));
    };

    // init node features
    k_movie_feat<<<(NM + 255) / 256, 256, 0, stream>>>(movie_x, mlw, mlb, movie_emb, movie_node_id, xm0, NM, F);
    k_gather_rows<<<2048, 256, 0, stream>>>(user_emb, user_node_id, xu0, NU);

    // layer 0: user <- rev(movie), movie <- rates(user)  [both read old xu0/xm0]
    sage_stage(xm0, rates_dst, rates_src, NU, xu0, iL0RE, iBN0U, xu1);
    sage_stage(xu0, rates_src, rates_dst, NM, xm0, iL0RA, iBN0M, xm1);
    // layer 1 [reads xu1/xm1]
    sage_stage(xm1, rates_dst, rates_src, NU, xu1, iL1RE, iBN1U, xu0);
    sage_stage(xu1, rates_src, rates_dst, NM, xm1, iL1RA, iBN1M, xm0);

    // classifier
    k_classifier<<<(L + 255) / 256, 256, 0, stream>>>(xu0, xm0, label_src, label_dst,
                                                      cls_w1, cls_b1, cls_w2, cls_b2,
                                                      (float*)d_out, L);
}

// Round 2
// 1222.349 us; speedup vs baseline: 1.5329x; 1.5329x over previous
//
#include <hip/hip_runtime.h>
#include <hip/hip_bf16.h>
#include <stdint.h>

#define HD 64
#define SCAN_CH 1024   // elements per scan block (256 threads x 4)

__device__ __forceinline__ void atomAddF(float* p, float v) {
    unsafeAtomicAdd(p, v);
}

// ---------------- CSR build ----------------

__global__ __launch_bounds__(256) void k_hist(const int* __restrict__ key,
                                              int* __restrict__ cnt, int E) {
    int t = blockIdx.x * blockDim.x + threadIdx.x;
    int stride = gridDim.x * blockDim.x;
    for (; t < E; t += stride) atomicAdd(&cnt[key[t]], 1);
}

__global__ __launch_bounds__(256) void k_scan_a(const int* __restrict__ cnt,
                                                int* __restrict__ partial, int N) {
    __shared__ int red[256];
    int b = blockIdx.x, t = threadIdx.x;
    int base = b * SCAN_CH + t * 4;
    int s = 0;
    #pragma unroll
    for (int i = 0; i < 4; ++i) if (base + i < N) s += cnt[base + i];
    red[t] = s; __syncthreads();
    for (int off = 128; off > 0; off >>= 1) {
        if (t < off) red[t] += red[t + off];
        __syncthreads();
    }
    if (t == 0) partial[b] = red[0];
}

__global__ void k_scan_b(int* __restrict__ partial, int nb) {
    __shared__ int sh[256];
    int t = threadIdx.x;
    int v = (t < nb) ? partial[t] : 0;
    sh[t] = v; __syncthreads();
    for (int off = 1; off < 256; off <<= 1) {
        int x = (t >= off) ? sh[t - off] : 0;
        __syncthreads();
        sh[t] += x;
        __syncthreads();
    }
    if (t < nb) partial[t] = sh[t] - v;   // exclusive
}

__global__ __launch_bounds__(256) void k_scan_c(const int* __restrict__ cnt,
                                                const int* __restrict__ partial,
                                                int* __restrict__ rp, int N, int E) {
    __shared__ int sh[256];
    int b = blockIdx.x, t = threadIdx.x;
    int base = b * SCAN_CH + t * 4;
    int v[4]; int s = 0;
    #pragma unroll
    for (int i = 0; i < 4; ++i) { v[i] = (base + i < N) ? cnt[base + i] : 0; s += v[i]; }
    sh[t] = s; __syncthreads();
    for (int off = 1; off < 256; off <<= 1) {
        int x = (t >= off) ? sh[t - off] : 0;
        __syncthreads();
        sh[t] += x;
        __syncthreads();
    }
    int run = partial[b] + sh[t] - s;     // exclusive offset for this thread's 4
    #pragma unroll
    for (int i = 0; i < 4; ++i) {
        if (base + i < N) rp[base + i] = run;
        run += v[i];
    }
    if (b == 0 && t == 0) rp[N] = E;
}

__global__ __launch_bounds__(256) void k_fill(const int* __restrict__ val,
                                              const int* __restrict__ key,
                                              const int* __restrict__ rp,
                                              int* __restrict__ cur,
                                              int* __restrict__ nbr, int E) {
    int t = blockIdx.x * blockDim.x + threadIdx.x;
    int stride = gridDim.x * blockDim.x;
    for (; t < E; t += stride) {
        int d = key[t];
        int pos = rp[d] + atomicAdd(&cur[d], 1);
        nbr[pos] = val[t];
    }
}

// ---------------- segmented mean-reduce (wave per dst node) ----------------

__global__ __launch_bounds__(256) void k_reduce_mean(
    const float* __restrict__ xsrc, const int* __restrict__ rp,
    const int* __restrict__ nbr, float* __restrict__ mean, int N)
{
    int wid = blockIdx.x * (blockDim.x >> 6) + (threadIdx.x >> 6);
    int lane = threadIdx.x & 63;
    if (wid >= N) return;
    int s0 = rp[wid], s1 = rp[wid + 1];
    float acc = 0.f;
    int k = s0;
    for (; k + 4 <= s1; k += 4) {
        int a = nbr[k], b = nbr[k + 1], c = nbr[k + 2], d = nbr[k + 3];
        float va = xsrc[(size_t)a * HD + lane];
        float vb = xsrc[(size_t)b * HD + lane];
        float vc = xsrc[(size_t)c * HD + lane];
        float vd = xsrc[(size_t)d * HD + lane];
        acc += va + vb + vc + vd;
    }
    for (; k < s1; ++k) acc += xsrc[(size_t)nbr[k] * HD + lane];
    int deg = s1 - s0;
    float inv = deg > 0 ? 1.f / (float)deg : 0.f;
    mean[(size_t)wid * HD + lane] = acc * inv;
}

// ---------------- dense per-node ops ----------------

__global__ __launch_bounds__(256) void k_movie_feat(
    const float* __restrict__ mx, const float* __restrict__ W,
    const float* __restrict__ b, const float* __restrict__ memb,
    const int* __restrict__ mids, float* __restrict__ xm, int NM, int F)
{
    int m = blockIdx.x * blockDim.x + threadIdx.x;
    if (m >= NM) return;
    const float* xr = mx + (size_t)m * F;
    float acc[HD];
    #pragma unroll
    for (int j = 0; j < HD; ++j) acc[j] = b[j];
    for (int f = 0; f < F; ++f) {
        float v = xr[f];
        #pragma unroll
        for (int j = 0; j < HD; ++j) acc[j] += v * W[f * HD + j];
    }
    int nid = mids[m];
    const float* er = memb + (size_t)nid * HD;
    float4* o = (float4*)(xm + (size_t)m * HD);
    #pragma unroll
    for (int j = 0; j < HD; j += 4) {
        float4 e = *(const float4*)(er + j);
        o[j >> 2] = make_float4(acc[j] + e.x, acc[j + 1] + e.y, acc[j + 2] + e.z, acc[j + 3] + e.w);
    }
}

__global__ __launch_bounds__(256) void k_gather_rows(
    const float* __restrict__ src, const int* __restrict__ idx,
    float* __restrict__ dst, int N)
{
    int t = blockIdx.x * blockDim.x + threadIdx.x;
    int total = N * HD;
    int stride = gridDim.x * blockDim.x;
    for (; t < total; t += stride) {
        int i = t >> 6, h = t & 63;
        dst[t] = src[(size_t)idx[i] * HD + h];
    }
}

// out[n] = mean[n] @ wl + bl + xdst[n] @ wr
__global__ __launch_bounds__(256) void k_sage_linear(
    const float* __restrict__ meanv, const float* __restrict__ xdst,
    const float* __restrict__ wl, const float* __restrict__ blv,
    const float* __restrict__ wr,
    float* __restrict__ out, int N)
{
    int n = blockIdx.x * blockDim.x + threadIdx.x;
    if (n >= N) return;
    const float* ag = meanv + (size_t)n * HD;
    const float* xd = xdst + (size_t)n * HD;
    float acc[HD];
    #pragma unroll
    for (int j = 0; j < HD; ++j) acc[j] = blv[j];
    for (int i = 0; i < HD; i += 4) {
        float4 m = *(const float4*)(ag + i);
        float4 x = *(const float4*)(xd + i);
        #pragma unroll
        for (int j = 0; j < HD; ++j) {
            acc[j] += m.x * wl[(i + 0) * HD + j] + m.y * wl[(i + 1) * HD + j]
                    + m.z * wl[(i + 2) * HD + j] + m.w * wl[(i + 3) * HD + j]
                    + x.x * wr[(i + 0) * HD + j] + x.y * wr[(i + 1) * HD + j]
                    + x.z * wr[(i + 2) * HD + j] + x.w * wr[(i + 3) * HD + j];
        }
    }
    float4* o = (float4*)(out + (size_t)n * HD);
    #pragma unroll
    for (int j = 0; j < HD; j += 4)
        o[j >> 2] = make_float4(acc[j], acc[j + 1], acc[j + 2], acc[j + 3]);
}

__global__ __launch_bounds__(256) void k_colstats(
    const float* __restrict__ x, float* __restrict__ stats, int N)
{
    __shared__ float ssum[HD], ssq[HD];
    if (threadIdx.x < HD) { ssum[threadIdx.x] = 0.f; ssq[threadIdx.x] = 0.f; }
    __syncthreads();
    const float4* x4 = (const float4*)x;
    int total4 = N * (HD / 4);
    int t = blockIdx.x * blockDim.x + threadIdx.x;
    int stride = gridDim.x * blockDim.x;
    int h = (t * 4) & 63;
    float s0 = 0, s1 = 0, s2 = 0, s3 = 0, q0 = 0, q1 = 0, q2 = 0, q3 = 0;
    for (; t < total4; t += stride) {
        float4 v = x4[t];
        s0 += v.x; q0 += v.x * v.x;
        s1 += v.y; q1 += v.y * v.y;
        s2 += v.z; q2 += v.z * v.z;
        s3 += v.w; q3 += v.w * v.w;
    }
    atomAddF(&ssum[h + 0], s0); atomAddF(&ssq[h + 0], q0);
    atomAddF(&ssum[h + 1], s1); atomAddF(&ssq[h + 1], q1);
    atomAddF(&ssum[h + 2], s2); atomAddF(&ssq[h + 2], q2);
    atomAddF(&ssum[h + 3], s3); atomAddF(&ssq[h + 3], q3);
    __syncthreads();
    if (threadIdx.x < HD) {
        atomAddF(&stats[threadIdx.x], ssum[threadIdx.x]);
        atomAddF(&stats[HD + threadIdx.x], ssq[threadIdx.x]);
    }
}

__global__ void k_bn_finalize(const float* __restrict__ stats,
                              const float* __restrict__ g, const float* __restrict__ b,
                              float* __restrict__ ss, int N)
{
    int j = threadIdx.x;
    if (j < HD) {
        float invN = 1.f / (float)N;
        float mu = stats[j] * invN;
        float var = stats[HD + j] * invN - mu * mu;
        var = var < 0.f ? 0.f : var;
        float sc = g[j] * rsqrtf(var + 1e-5f);
        ss[j] = sc;
        ss[HD + j] = b[j] - mu * sc;
    }
}

__global__ __launch_bounds__(256) void k_bn_relu(
    float4* __restrict__ x, const float* __restrict__ ss, int total4)
{
    int t = blockIdx.x * blockDim.x + threadIdx.x;
    int stride = gridDim.x * blockDim.x;
    for (; t < total4; t += stride) {
        int h = (t * 4) & 63;
        float4 v = x[t];
        v.x = fmaxf(v.x * ss[h + 0] + ss[HD + h + 0], 0.f);
        v.y = fmaxf(v.y * ss[h + 1] + ss[HD + h + 1], 0.f);
        v.z = fmaxf(v.z * ss[h + 2] + ss[HD + h + 2], 0.f);
        v.w = fmaxf(v.w * ss[h + 3] + ss[HD + h + 3], 0.f);
        x[t] = v;
    }
}

__global__ __launch_bounds__(256) void k_classifier(
    const float* __restrict__ xu, const float* __restrict__ xm,
    const int* __restrict__ lsrc, const int* __restrict__ ldst,
    const float* __restrict__ w1, const float* __restrict__ b1,
    const float* __restrict__ w2, const float* __restrict__ b2,
    float* __restrict__ out, int L)
{
    int l = blockIdx.x * blockDim.x + threadIdx.x;
    if (l >= L) return;
    const float* ur = xu + (size_t)lsrc[l] * HD;
    const float* mr = xm + (size_t)ldst[l] * HD;
    float acc[HD];
    #pragma unroll
    for (int j = 0; j < HD; ++j) acc[j] = b1[j];
    for (int i = 0; i < HD; i += 4) {
        float4 a = *(const float4*)(ur + i);
        #pragma unroll
        for (int j = 0; j < HD; ++j)
            acc[j] += a.x * w1[(i + 0) * HD + j] + a.y * w1[(i + 1) * HD + j]
                    + a.z * w1[(i + 2) * HD + j] + a.w * w1[(i + 3) * HD + j];
    }
    for (int i = 0; i < HD; i += 4) {
        float4 a = *(const float4*)(mr + i);
        #pragma unroll
        for (int j = 0; j < HD; ++j)
            acc[j] += a.x * w1[(HD + i + 0) * HD + j] + a.y * w1[(HD + i + 1) * HD + j]
                    + a.z * w1[(HD + i + 2) * HD + j] + a.w * w1[(HD + i + 3) * HD + j];
    }
    float r = b2[0];
    #pragma unroll
    for (int j = 0; j < HD; ++j) r += fmaxf(acc[j], 0.f) * w2[j];
    out[l] = r;
}

extern "C" void kernel_launch(void* const* d_in, const int* in_sizes, int n_in,
                              void* d_out, int out_size, void* d_ws, size_t ws_size,
                              hipStream_t stream) {
    (void)n_in; (void)ws_size;
    const int NU = in_sizes[1] / HD;
    const int NM = in_sizes[2] / HD;
    const int F  = in_sizes[0] / NM;
    const int E  = in_sizes[31];
    const int L  = out_size;

    int iL0RA, iL0RE, iL1RA, iL1RE, iBN0U, iBN0M, iBN1U, iBN1M;
    if (in_sizes[11] == HD) {          // setup-dict order
        iL0RA = 5; iL0RE = 8; iBN0U = 11; iBN0M = 13;
        iL1RA = 15; iL1RE = 18; iBN1U = 21; iBN1M = 23;
    } else {                           // reference-signature order
        iL0RA = 5; iL0RE = 8; iL1RA = 11; iL1RE = 14;
        iBN0U = 17; iBN0M = 19; iBN1U = 21; iBN1M = 23;
    }
    const float* movie_x   = (const float*)d_in[0];
    const float* user_emb  = (const float*)d_in[1];
    const float* movie_emb = (const float*)d_in[2];
    const float* mlw       = (const float*)d_in[3];
    const float* mlb       = (const float*)d_in[4];
    const float* cls_w1    = (const float*)d_in[25];
    const float* cls_b1    = (const float*)d_in[26];
    const float* cls_w2    = (const float*)d_in[27];
    const float* cls_b2    = (const float*)d_in[28];
    const int* user_node_id  = (const int*)d_in[29];
    const int* movie_node_id = (const int*)d_in[30];
    const int* rates_src   = (const int*)d_in[31];
    const int* rates_dst   = (const int*)d_in[32];
    const int* label_src   = (const int*)d_in[33];
    const int* label_dst   = (const int*)d_in[34];

    // ---- workspace layout ----
    char* wsb = (char*)d_ws;
    float* xu0 = (float*)wsb;                    wsb += (size_t)NU * HD * 4;
    float* xu1 = (float*)wsb;                    wsb += (size_t)NU * HD * 4;
    float* xm0 = (float*)wsb;                    wsb += (size_t)NM * HD * 4;
    float* xm1 = (float*)wsb;                    wsb += (size_t)NM * HD * 4;
    float* agg = (float*)wsb;                    wsb += (size_t)NU * HD * 4;   // max(NU,NM) rows
    int* rp_m  = (int*)wsb;                      wsb += (size_t)(NM + 1) * 4;
    int* rp_u  = (int*)wsb;                      wsb += (size_t)(NU + 1) * 4;
    int* cur   = (int*)wsb;                      wsb += (size_t)NU * 4;        // max(NU,NM)
    int* nbr_m = (int*)wsb;                      wsb += (size_t)E * 4;
    int* nbr_u = (int*)wsb;                      wsb += (size_t)E * 4;
    int* partial = (int*)wsb;                    wsb += 256 * 4;
    float* stats = (float*)wsb;                  wsb += 2 * HD * 4;
    float* ss    = (float*)wsb;                  wsb += 2 * HD * 4;

    const int egrid = (E + 255) / 256;

    // ---- CSR build: movie-dst (key = rates_dst, val = rates_src) ----
    {
        int nb = (NM + SCAN_CH - 1) / SCAN_CH;
        hipMemsetAsync(cur, 0, (size_t)NM * 4, stream);
        k_hist<<<egrid, 256, 0, stream>>>(rates_dst, cur, E);
        k_scan_a<<<nb, 256, 0, stream>>>(cur, partial, NM);
        k_scan_b<<<1, 256, 0, stream>>>(partial, nb);
        k_scan_c<<<nb, 256, 0, stream>>>(cur, partial, rp_m, NM, E);
        hipMemsetAsync(cur, 0, (size_t)NM * 4, stream);
        k_fill<<<egrid, 256, 0, stream>>>(rates_src, rates_dst, rp_m, cur, nbr_m, E);
    }
    // ---- CSR build: user-dst (key = rates_src, val = rates_dst) ----
    {
        int nb = (NU + SCAN_CH - 1) / SCAN_CH;
        hipMemsetAsync(cur, 0, (size_t)NU * 4, stream);
        k_hist<<<egrid, 256, 0, stream>>>(rates_src, cur, E);
        k_scan_a<<<nb, 256, 0, stream>>>(cur, partial, NU);
        k_scan_b<<<1, 256, 0, stream>>>(partial, nb);
        k_scan_c<<<nb, 256, 0, stream>>>(cur, partial, rp_u, NU, E);
        hipMemsetAsync(cur, 0, (size_t)NU * 4, stream);
        k_fill<<<egrid, 256, 0, stream>>>(rates_dst, rates_src, rp_u, cur, nbr_u, E);
    }

    // ---- init node features ----
    k_movie_feat<<<(NM + 255) / 256, 256, 0, stream>>>(movie_x, mlw, mlb, movie_emb, movie_node_id, xm0, NM, F);
    k_gather_rows<<<2048, 256, 0, stream>>>(user_emb, user_node_id, xu0, NU);

    auto sage_stage = [&](const float* xsrc, const int* rp, const int* nbr, int Ndst,
                          const float* xdst, int iW, int iBN, float* outBuf) {
        const float* wl = (const float*)d_in[iW + 0];
        const float* bl = (const float*)d_in[iW + 1];
        const float* wr = (const float*)d_in[iW + 2];
        const float* g  = (const float*)d_in[iBN + 0];
        const float* bb = (const float*)d_in[iBN + 1];
        k_reduce_mean<<<(Ndst + 3) / 4, 256, 0, stream>>>(xsrc, rp, nbr, agg, Ndst);
        k_sage_linear<<<(Ndst + 255) / 256, 256, 0, stream>>>(agg, xdst, wl, bl, wr, outBuf, Ndst);
        hipMemsetAsync(stats, 0, 2 * HD * 4, stream);
        k_colstats<<<1024, 256, 0, stream>>>(outBuf, stats, Ndst);
        k_bn_finalize<<<1, 64, 0, stream>>>(stats, g, bb, ss, Ndst);
        k_bn_relu<<<1024, 256, 0, stream>>>((float4*)outBuf, ss, Ndst * (HD / 4));
    };

    // layer 0: user <- rev(movie), movie <- rates(user)  [both read xu0/xm0]
    sage_stage(xm0, rp_u, nbr_u, NU, xu0, iL0RE, iBN0U, xu1);
    sage_stage(xu0, rp_m, nbr_m, NM, xm0, iL0RA, iBN0M, xm1);
    // layer 1 [reads xu1/xm1]
    sage_stage(xm1, rp_u, nbr_u, NU, xu1, iL1RE, iBN1U, xu0);
    sage_stage(xu1, rp_m, nbr_m, NM, xm1, iL1RA, iBN1M, xm0);

    k_classifier<<<(L + 255) / 256, 256, 0, stream>>>(xu0, xm0, label_src, label_dst,
                                                      cls_w1, cls_b1, cls_w2, cls_b2,
                                                      (float*)d_out, L);
}

// Round 3
// 642.145 us; speedup vs baseline: 2.9180x; 1.9035x over previous
//
#include <hip/hip_runtime.h>
#include <hip/hip_bf16.h>
#include <stdint.h>

#define HD 64
#define SCAN_CH 1024

typedef __bf16 bf16x8 __attribute__((ext_vector_type(8)));
typedef float f32x4 __attribute__((ext_vector_type(4)));

__device__ __forceinline__ void atomAddF(float* p, float v) {
    unsafeAtomicAdd(p, v);
}
__device__ __forceinline__ ushort f2bf(float v) {
    __hip_bfloat16 h = __float2bfloat16(v);
    return *(ushort*)&h;
}
__device__ __forceinline__ float bf2f(ushort u) {
    return __uint_as_float(((uint)u) << 16);
}
__device__ __forceinline__ uint pack2(float a, float b) {
    return (uint)f2bf(a) | ((uint)f2bf(b) << 16);
}

// ---------------- CSR build ----------------

__global__ __launch_bounds__(256) void k_hist(const int* __restrict__ key,
                                              int* __restrict__ cnt, int E) {
    int t = blockIdx.x * blockDim.x + threadIdx.x;
    int stride = gridDim.x * blockDim.x;
    for (; t < E; t += stride) atomicAdd(&cnt[key[t]], 1);
}

__global__ __launch_bounds__(256) void k_scan_a(const int* __restrict__ cnt,
                                                int* __restrict__ partial, int N) {
    __shared__ int red[256];
    int b = blockIdx.x, t = threadIdx.x;
    int base = b * SCAN_CH + t * 4;
    int s = 0;
    #pragma unroll
    for (int i = 0; i < 4; ++i) if (base + i < N) s += cnt[base + i];
    red[t] = s; __syncthreads();
    for (int off = 128; off > 0; off >>= 1) {
        if (t < off) red[t] += red[t + off];
        __syncthreads();
    }
    if (t == 0) partial[b] = red[0];
}

__global__ void k_scan_b(int* __restrict__ partial, int nb) {
    __shared__ int sh[256];
    int t = threadIdx.x;
    int v = (t < nb) ? partial[t] : 0;
    sh[t] = v; __syncthreads();
    for (int off = 1; off < 256; off <<= 1) {
        int x = (t >= off) ? sh[t - off] : 0;
        __syncthreads();
        sh[t] += x;
        __syncthreads();
    }
    if (t < nb) partial[t] = sh[t] - v;   // exclusive
}

__global__ __launch_bounds__(256) void k_scan_c(const int* __restrict__ cnt,
                                                const int* __restrict__ partial,
                                                int* __restrict__ rp, int N, int E) {
    __shared__ int sh[256];
    int b = blockIdx.x, t = threadIdx.x;
    int base = b * SCAN_CH + t * 4;
    int v[4]; int s = 0;
    #pragma unroll
    for (int i = 0; i < 4; ++i) { v[i] = (base + i < N) ? cnt[base + i] : 0; s += v[i]; }
    sh[t] = s; __syncthreads();
    for (int off = 1; off < 256; off <<= 1) {
        int x = (t >= off) ? sh[t - off] : 0;
        __syncthreads();
        sh[t] += x;
        __syncthreads();
    }
    int run = partial[b] + sh[t] - s;
    #pragma unroll
    for (int i = 0; i < 4; ++i) {
        if (base + i < N) rp[base + i] = run;
        run += v[i];
    }
    if (b == 0 && t == 0) rp[N] = E;
}

__global__ __launch_bounds__(256) void k_fill(const int* __restrict__ val,
                                              const int* __restrict__ key,
                                              const int* __restrict__ rp,
                                              int* __restrict__ cur,
                                              int* __restrict__ nbr, int E) {
    int t = blockIdx.x * blockDim.x + threadIdx.x;
    int stride = gridDim.x * blockDim.x;
    for (; t < E; t += stride) {
        int d = key[t];
        int pos = rp[d] + atomicAdd(&cur[d], 1);
        nbr[pos] = val[t];
    }
}

// ---------------- weight fragment packing ----------------
// dst[t], t = (((kk*4+nn)*64+lane)*8+e): B[k][col], k=(lane>>4)*8+e+32*kk,
// col=(lane&15)+16*nn. k<64 -> wlo[k][col]; else whi[k-64][col].
__global__ void k_pack_w(const float* __restrict__ wlo, const float* __restrict__ whi,
                         ushort* __restrict__ dst) {
    int t = blockIdx.x * blockDim.x + threadIdx.x;   // 8192 threads
    int e = t & 7, lane = (t >> 3) & 63, nn = (t >> 9) & 3, kk = t >> 11;
    int k = (lane >> 4) * 8 + e + 32 * kk;
    int col = (lane & 15) + 16 * nn;
    float v = (k < 64) ? wlo[k * 64 + col] : whi[(k - 64) * 64 + col];
    dst[t] = f2bf(v);
}

// ---------------- segmented mean-reduce (wave per dst node, bf16) ----------------

__global__ __launch_bounds__(256) void k_reduce_mean(
    const ushort* __restrict__ xsrc, const int* __restrict__ rp,
    const int* __restrict__ nbr, ushort* __restrict__ mean, int N)
{
    int wid = blockIdx.x * 4 + (threadIdx.x >> 6);
    int lane = threadIdx.x & 63;
    if (wid >= N) return;
    int s0 = rp[wid], s1 = rp[wid + 1];
    float acc = 0.f;
    int k = s0;
    for (; k + 4 <= s1; k += 4) {
        int a = nbr[k], b = nbr[k + 1], c = nbr[k + 2], d = nbr[k + 3];
        float va = bf2f(xsrc[(size_t)a * HD + lane]);
        float vb = bf2f(xsrc[(size_t)b * HD + lane]);
        float vc = bf2f(xsrc[(size_t)c * HD + lane]);
        float vd = bf2f(xsrc[(size_t)d * HD + lane]);
        acc += va + vb + vc + vd;
    }
    for (; k < s1; ++k) acc += bf2f(xsrc[(size_t)nbr[k] * HD + lane]);
    float inv = (s1 > s0) ? 1.f / (float)(s1 - s0) : 0.f;
    mean[(size_t)wid * HD + lane] = f2bf(acc * inv);
}

// ---------------- MFMA GEMM: out[N][64] = [mean | xdst] @ Wcat + bias ----------------

__global__ __launch_bounds__(256) void k_sage_mfma(
    const ushort* __restrict__ meanb, const ushort* __restrict__ xdst,
    const ushort* __restrict__ wp, const float* __restrict__ blv,
    ushort* __restrict__ out, int N)
{
    int wave = threadIdx.x >> 6, lane = threadIdx.x & 63;
    int n0 = blockIdx.x * 64 + wave * 16;
    if (n0 >= N) return;
    int lrow = lane & 15, lk = lane >> 4;
    int arow = n0 + lrow; if (arow >= N) arow = N - 1;
    const ushort* pm = meanb + (size_t)arow * HD + lk * 8;
    const ushort* px = xdst  + (size_t)arow * HD + lk * 8;
    const bf16x8* wpv = (const bf16x8*)wp + lane;

    bf16x8 b[4][4];
    #pragma unroll
    for (int kk = 0; kk < 4; ++kk)
        #pragma unroll
        for (int nn = 0; nn < 4; ++nn)
            b[kk][nn] = wpv[(kk * 4 + nn) * 64];

    f32x4 acc[4];
    #pragma unroll
    for (int nn = 0; nn < 4; ++nn) acc[nn] = (f32x4){0.f, 0.f, 0.f, 0.f};

    #pragma unroll
    for (int kk = 0; kk < 4; ++kk) {
        const ushort* src = (kk < 2) ? (pm + 32 * kk) : (px + 32 * (kk - 2));
        bf16x8 a = *(const bf16x8*)src;
        #pragma unroll
        for (int nn = 0; nn < 4; ++nn)
            acc[nn] = __builtin_amdgcn_mfma_f32_16x16x32_bf16(a, b[kk][nn], acc[nn], 0, 0, 0);
    }

    #pragma unroll
    for (int nn = 0; nn < 4; ++nn) {
        float bias = blv[lrow + 16 * nn];
        #pragma unroll
        for (int r = 0; r < 4; ++r) {
            int orow = n0 + lk * 4 + r;
            if (orow < N)
                out[(size_t)orow * HD + lrow + 16 * nn] = f2bf(acc[nn][r] + bias);
        }
    }
}

// ---------------- classifier: relu(A @ W1 + b1) @ w2 + b2 ----------------

__global__ __launch_bounds__(256) void k_cls_mfma(
    const ushort* __restrict__ xu, const ushort* __restrict__ xm,
    const int* __restrict__ lsrc, const int* __restrict__ ldst,
    const ushort* __restrict__ wp, const float* __restrict__ b1,
    const float* __restrict__ w2, const float* __restrict__ b2,
    float* __restrict__ out, int L)
{
    int wave = threadIdx.x >> 6, lane = threadIdx.x & 63;
    int l0 = blockIdx.x * 64 + wave * 16;
    if (l0 >= L) return;
    int lrow = lane & 15, lk = lane >> 4;
    int li = l0 + lrow; if (li >= L) li = L - 1;
    const ushort* pu = xu + (size_t)lsrc[li] * HD + lk * 8;
    const ushort* pm = xm + (size_t)ldst[li] * HD + lk * 8;
    const bf16x8* wpv = (const bf16x8*)wp + lane;

    f32x4 acc[4];
    #pragma unroll
    for (int nn = 0; nn < 4; ++nn) acc[nn] = (f32x4){0.f, 0.f, 0.f, 0.f};

    #pragma unroll
    for (int kk = 0; kk < 4; ++kk) {
        const ushort* src = (kk < 2) ? (pu + 32 * kk) : (pm + 32 * (kk - 2));
        bf16x8 a = *(const bf16x8*)src;
        #pragma unroll
        for (int nn = 0; nn < 4; ++nn)
            acc[nn] = __builtin_amdgcn_mfma_f32_16x16x32_bf16(a, wpv[(kk * 4 + nn) * 64], acc[nn], 0, 0, 0);
    }

    float p0 = 0.f, p1 = 0.f, p2 = 0.f, p3 = 0.f;
    #pragma unroll
    for (int nn = 0; nn < 4; ++nn) {
        int c = lrow + 16 * nn;
        float bb = b1[c], w = w2[c];
        p0 += fmaxf(acc[nn][0] + bb, 0.f) * w;
        p1 += fmaxf(acc[nn][1] + bb, 0.f) * w;
        p2 += fmaxf(acc[nn][2] + bb, 0.f) * w;
        p3 += fmaxf(acc[nn][3] + bb, 0.f) * w;
    }
    #pragma unroll
    for (int off = 1; off < 16; off <<= 1) {
        p0 += __shfl_xor(p0, off);
        p1 += __shfl_xor(p1, off);
        p2 += __shfl_xor(p2, off);
        p3 += __shfl_xor(p3, off);
    }
    if (lrow == 0) {
        float bb2 = b2[0];
        int r0 = l0 + lk * 4;
        if (r0 + 0 < L) out[r0 + 0] = p0 + bb2;
        if (r0 + 1 < L) out[r0 + 1] = p1 + bb2;
        if (r0 + 2 < L) out[r0 + 2] = p2 + bb2;
        if (r0 + 3 < L) out[r0 + 3] = p3 + bb2;
    }
}

// ---------------- dense init ----------------

__global__ __launch_bounds__(256) void k_movie_feat(
    const float* __restrict__ mx, const float* __restrict__ W,
    const float* __restrict__ b, const float* __restrict__ memb,
    const int* __restrict__ mids, ushort* __restrict__ xm, int NM, int F)
{
    int m = blockIdx.x * blockDim.x + threadIdx.x;
    if (m >= NM) return;
    const float* xr = mx + (size_t)m * F;
    float acc[HD];
    #pragma unroll
    for (int j = 0; j < HD; ++j) acc[j] = b[j];
    for (int f = 0; f < F; ++f) {
        float v = xr[f];
        #pragma unroll
        for (int j = 0; j < HD; ++j) acc[j] += v * W[f * HD + j];
    }
    int nid = mids[m];
    const float* er = memb + (size_t)nid * HD;
    uint* o = (uint*)(xm + (size_t)m * HD);
    #pragma unroll
    for (int j = 0; j < HD; j += 2)
        o[j >> 1] = pack2(acc[j] + er[j], acc[j + 1] + er[j + 1]);
}

__global__ __launch_bounds__(256) void k_gather_rows(
    const float* __restrict__ src, const int* __restrict__ idx,
    ushort* __restrict__ dst, int N)
{
    int t = blockIdx.x * blockDim.x + threadIdx.x;
    int total = N * HD;
    int stride = gridDim.x * blockDim.x;
    for (; t < total; t += stride) {
        int i = t >> 6, h = t & 63;
        dst[t] = f2bf(src[(size_t)idx[i] * HD + h]);
    }
}

// ---------------- BN (bf16 I/O) ----------------

__global__ __launch_bounds__(256) void k_colstats(
    const ushort* __restrict__ x, float* __restrict__ stats, int N)
{
    __shared__ float ssum[HD], ssq[HD];
    if (threadIdx.x < HD) { ssum[threadIdx.x] = 0.f; ssq[threadIdx.x] = 0.f; }
    __syncthreads();
    const uint4* x4 = (const uint4*)x;
    int total4 = N * 8;                    // 8 bf16 per uint4, 8 uint4 per row
    int t = blockIdx.x * blockDim.x + threadIdx.x;
    int stride = gridDim.x * blockDim.x;   // multiple of 8 -> column set fixed
    int h = (t & 7) * 8;
    float s[8] = {0,0,0,0,0,0,0,0}, q[8] = {0,0,0,0,0,0,0,0};
    for (; t < total4; t += stride) {
        uint4 u = x4[t];
        uint w[4] = {u.x, u.y, u.z, u.w};
        #pragma unroll
        for (int i = 0; i < 4; ++i) {
            float f0 = __uint_as_float(w[i] << 16);
            float f1 = __uint_as_float(w[i] & 0xffff0000u);
            s[2*i] += f0;   q[2*i] += f0 * f0;
            s[2*i+1] += f1; q[2*i+1] += f1 * f1;
        }
    }
    #pragma unroll
    for (int i = 0; i < 8; ++i) { atomAddF(&ssum[h + i], s[i]); atomAddF(&ssq[h + i], q[i]); }
    __syncthreads();
    if (threadIdx.x < HD) {
        atomAddF(&stats[threadIdx.x], ssum[threadIdx.x]);
        atomAddF(&stats[HD + threadIdx.x], ssq[threadIdx.x]);
    }
}

__global__ void k_bn_finalize(const float* __restrict__ stats,
                              const float* __restrict__ g, const float* __restrict__ b,
                              float* __restrict__ ss, int N)
{
    int j = threadIdx.x;
    if (j < HD) {
        float invN = 1.f / (float)N;
        float mu = stats[j] * invN;
        float var = stats[HD + j] * invN - mu * mu;
        var = var < 0.f ? 0.f : var;
        float sc = g[j] * rsqrtf(var + 1e-5f);
        ss[j] = sc;
        ss[HD + j] = b[j] - mu * sc;
    }
}

__global__ __launch_bounds__(256) void k_bn_relu(
    uint4* __restrict__ x, const float* __restrict__ ss, int total4)
{
    int t = blockIdx.x * blockDim.x + threadIdx.x;
    int stride = gridDim.x * blockDim.x;
    for (; t < total4; t += stride) {
        int h = (t & 7) * 8;
        uint4 u = x[t];
        uint w[4] = {u.x, u.y, u.z, u.w};
        #pragma unroll
        for (int i = 0; i < 4; ++i) {
            float f0 = __uint_as_float(w[i] << 16);
            float f1 = __uint_as_float(w[i] & 0xffff0000u);
            f0 = fmaxf(f0 * ss[h + 2*i] + ss[HD + h + 2*i], 0.f);
            f1 = fmaxf(f1 * ss[h + 2*i+1] + ss[HD + h + 2*i+1], 0.f);
            w[i] = pack2(f0, f1);
        }
        x[t] = make_uint4(w[0], w[1], w[2], w[3]);
    }
}

extern "C" void kernel_launch(void* const* d_in, const int* in_sizes, int n_in,
                              void* d_out, int out_size, void* d_ws, size_t ws_size,
                              hipStream_t stream) {
    (void)n_in; (void)ws_size;
    const int NU = in_sizes[1] / HD;
    const int NM = in_sizes[2] / HD;
    const int F  = in_sizes[0] / NM;
    const int E  = in_sizes[31];
    const int L  = out_size;

    int iL0RA, iL0RE, iL1RA, iL1RE, iBN0U, iBN0M, iBN1U, iBN1M;
    if (in_sizes[11] == HD) {          // setup-dict order
        iL0RA = 5; iL0RE = 8; iBN0U = 11; iBN0M = 13;
        iL1RA = 15; iL1RE = 18; iBN1U = 21; iBN1M = 23;
    } else {                           // reference-signature order
        iL0RA = 5; iL0RE = 8; iL1RA = 11; iL1RE = 14;
        iBN0U = 17; iBN0M = 19; iBN1U = 21; iBN1M = 23;
    }
    const float* movie_x   = (const float*)d_in[0];
    const float* user_emb  = (const float*)d_in[1];
    const float* movie_emb = (const float*)d_in[2];
    const float* mlw       = (const float*)d_in[3];
    const float* mlb       = (const float*)d_in[4];
    const float* cls_w1    = (const float*)d_in[25];
    const float* cls_b1    = (const float*)d_in[26];
    const float* cls_w2    = (const float*)d_in[27];
    const float* cls_b2    = (const float*)d_in[28];
    const int* user_node_id  = (const int*)d_in[29];
    const int* movie_node_id = (const int*)d_in[30];
    const int* rates_src   = (const int*)d_in[31];
    const int* rates_dst   = (const int*)d_in[32];
    const int* label_src   = (const int*)d_in[33];
    const int* label_dst   = (const int*)d_in[34];

    // ---- workspace layout (256B-aligned chunks) ----
    char* wsb = (char*)d_ws;
    auto alloc = [&](size_t bytes) { char* p = wsb; wsb += (bytes + 255) & ~(size_t)255; return p; };
    ushort* xu0 = (ushort*)alloc((size_t)NU * HD * 2);
    ushort* xu1 = (ushort*)alloc((size_t)NU * HD * 2);
    ushort* xm0 = (ushort*)alloc((size_t)NM * HD * 2);
    ushort* xm1 = (ushort*)alloc((size_t)NM * HD * 2);
    ushort* meanb = (ushort*)alloc((size_t)(NU > NM ? NU : NM) * HD * 2);
    ushort* wp0 = (ushort*)alloc(8192 * 2);   // l0 rev (user stage)
    ushort* wp1 = (ushort*)alloc(8192 * 2);   // l0 rates (movie stage)
    ushort* wp2 = (ushort*)alloc(8192 * 2);   // l1 rev
    ushort* wp3 = (ushort*)alloc(8192 * 2);   // l1 rates
    ushort* wpc = (ushort*)alloc(8192 * 2);   // classifier w1
    int* rp_m  = (int*)alloc((size_t)(NM + 1) * 4);
    int* rp_u  = (int*)alloc((size_t)(NU + 1) * 4);
    int* cur   = (int*)alloc((size_t)(NU > NM ? NU : NM) * 4);
    int* nbr_m = (int*)alloc((size_t)E * 4);
    int* nbr_u = (int*)alloc((size_t)E * 4);
    int* partial = (int*)alloc(256 * 4);
    float* stats = (float*)alloc(2 * HD * 4);
    float* ss    = (float*)alloc(2 * HD * 4);

    const int egrid = (E + 255) / 256;

    // ---- weight packing (independent of everything else) ----
    k_pack_w<<<32, 256, 0, stream>>>((const float*)d_in[iL0RE + 0], (const float*)d_in[iL0RE + 2], wp0);
    k_pack_w<<<32, 256, 0, stream>>>((const float*)d_in[iL0RA + 0], (const float*)d_in[iL0RA + 2], wp1);
    k_pack_w<<<32, 256, 0, stream>>>((const float*)d_in[iL1RE + 0], (const float*)d_in[iL1RE + 2], wp2);
    k_pack_w<<<32, 256, 0, stream>>>((const float*)d_in[iL1RA + 0], (const float*)d_in[iL1RA + 2], wp3);
    k_pack_w<<<32, 256, 0, stream>>>(cls_w1, cls_w1 + 64 * 64, wpc);

    // ---- CSR build: movie-dst ----
    {
        int nb = (NM + SCAN_CH - 1) / SCAN_CH;
        hipMemsetAsync(cur, 0, (size_t)NM * 4, stream);
        k_hist<<<egrid, 256, 0, stream>>>(rates_dst, cur, E);
        k_scan_a<<<nb, 256, 0, stream>>>(cur, partial, NM);
        k_scan_b<<<1, 256, 0, stream>>>(partial, nb);
        k_scan_c<<<nb, 256, 0, stream>>>(cur, partial, rp_m, NM, E);
        hipMemsetAsync(cur, 0, (size_t)NM * 4, stream);
        k_fill<<<egrid, 256, 0, stream>>>(rates_src, rates_dst, rp_m, cur, nbr_m, E);
    }
    // ---- CSR build: user-dst ----
    {
        int nb = (NU + SCAN_CH - 1) / SCAN_CH;
        hipMemsetAsync(cur, 0, (size_t)NU * 4, stream);
        k_hist<<<egrid, 256, 0, stream>>>(rates_src, cur, E);
        k_scan_a<<<nb, 256, 0, stream>>>(cur, partial, NU);
        k_scan_b<<<1, 256, 0, stream>>>(partial, nb);
        k_scan_c<<<nb, 256, 0, stream>>>(cur, partial, rp_u, NU, E);
        hipMemsetAsync(cur, 0, (size_t)NU * 4, stream);
        k_fill<<<egrid, 256, 0, stream>>>(rates_dst, rates_src, rp_u, cur, nbr_u, E);
    }

    // ---- init node features (bf16) ----
    k_movie_feat<<<(NM + 255) / 256, 256, 0, stream>>>(movie_x, mlw, mlb, movie_emb, movie_node_id, xm0, NM, F);
    k_gather_rows<<<2048, 256, 0, stream>>>(user_emb, user_node_id, xu0, NU);

    auto sage_stage = [&](const ushort* xsrc, const int* rp, const int* nbr, int Ndst,
                          const ushort* xdst, const ushort* wp, int iW, int iBN, ushort* outBuf) {
        const float* bl = (const float*)d_in[iW + 1];
        const float* g  = (const float*)d_in[iBN + 0];
        const float* bb = (const float*)d_in[iBN + 1];
        k_reduce_mean<<<(Ndst + 3) / 4, 256, 0, stream>>>(xsrc, rp, nbr, meanb, Ndst);
        k_sage_mfma<<<(Ndst + 63) / 64, 256, 0, stream>>>(meanb, xdst, wp, bl, outBuf, Ndst);
        hipMemsetAsync(stats, 0, 2 * HD * 4, stream);
        k_colstats<<<1024, 256, 0, stream>>>(outBuf, stats, Ndst);
        k_bn_finalize<<<1, 64, 0, stream>>>(stats, g, bb, ss, Ndst);
        k_bn_relu<<<1024, 256, 0, stream>>>((uint4*)outBuf, ss, Ndst * 8);
    };

    // layer 0: user <- rev(movie), movie <- rates(user)  [both read xu0/xm0]
    sage_stage(xm0, rp_u, nbr_u, NU, xu0, wp0, iL0RE, iBN0U, xu1);
    sage_stage(xu0, rp_m, nbr_m, NM, xm0, wp1, iL0RA, iBN0M, xm1);
    // layer 1 [reads xu1/xm1]
    sage_stage(xm1, rp_u, nbr_u, NU, xu1, wp2, iL1RE, iBN1U, xu0);
    sage_stage(xu1, rp_m, nbr_m, NM, xm1, wp3, iL1RA, iBN1M, xm0);

    k_cls_mfma<<<(L + 63) / 64, 256, 0, stream>>>(xu0, xm0, label_src, label_dst,
                                                  wpc, cls_b1, cls_w2, cls_b2,
                                                  (float*)d_out, L);
}

// Round 4
// 486.138 us; speedup vs baseline: 3.8544x; 1.3209x over previous
//
#include <hip/hip_runtime.h>
#include <hip/hip_bf16.h>
#include <stdint.h>

#define HD 64
#define SCAN_CH 1024
#define CHUNK 4096
#define EPT 16
#define BSHIFT 9
#define BSIZE 512

typedef __bf16 bf16x8 __attribute__((ext_vector_type(8)));
typedef float f32x4 __attribute__((ext_vector_type(4)));

__device__ __forceinline__ void atomAddF(float* p, float v) { unsafeAtomicAdd(p, v); }
__device__ __forceinline__ ushort f2bf(float v) {
    __hip_bfloat16 h = __float2bfloat16(v);
    return *(ushort*)&h;
}
__device__ __forceinline__ float bf2f(ushort u) {
    return __uint_as_float(((uint)u) << 16);
}
__device__ __forceinline__ uint pack2(float a, float b) {
    return (uint)f2bf(a) | ((uint)f2bf(b) << 16);
}

// ---------------- CSR build ----------------

__global__ __launch_bounds__(256) void k_hist2(const int* __restrict__ src,
                                               const int* __restrict__ dst,
                                               int* __restrict__ cnt_u,
                                               int* __restrict__ cnt_m, int E) {
    int t = blockIdx.x * blockDim.x + threadIdx.x;
    int stride = gridDim.x * blockDim.x;
    for (; t < E; t += stride) {
        atomicAdd(&cnt_u[src[t]], 1);
        atomicAdd(&cnt_m[dst[t]], 1);
    }
}

__global__ __launch_bounds__(256) void k_scan_a(const int* __restrict__ cnt,
                                                int* __restrict__ partial, int N) {
    __shared__ int red[256];
    int b = blockIdx.x, t = threadIdx.x;
    int base = b * SCAN_CH + t * 4;
    int s = 0;
    #pragma unroll
    for (int i = 0; i < 4; ++i) if (base + i < N) s += cnt[base + i];
    red[t] = s; __syncthreads();
    for (int off = 128; off > 0; off >>= 1) {
        if (t < off) red[t] += red[t + off];
        __syncthreads();
    }
    if (t == 0) partial[b] = red[0];
}

__global__ void k_scan_b(int* __restrict__ partial, int nb) {
    __shared__ int sh[256];
    int t = threadIdx.x;
    int v = (t < nb) ? partial[t] : 0;
    sh[t] = v; __syncthreads();
    for (int off = 1; off < 256; off <<= 1) {
        int x = (t >= off) ? sh[t - off] : 0;
        __syncthreads();
        sh[t] += x;
        __syncthreads();
    }
    if (t < nb) partial[t] = sh[t] - v;
}

__global__ __launch_bounds__(256) void k_scan_c(const int* __restrict__ cnt,
                                                const int* __restrict__ partial,
                                                int* __restrict__ rp, int N, int E) {
    __shared__ int sh[256];
    int b = blockIdx.x, t = threadIdx.x;
    int base = b * SCAN_CH + t * 4;
    int v[4]; int s = 0;
    #pragma unroll
    for (int i = 0; i < 4; ++i) { v[i] = (base + i < N) ? cnt[base + i] : 0; s += v[i]; }
    sh[t] = s; __syncthreads();
    for (int off = 1; off < 256; off <<= 1) {
        int x = (t >= off) ? sh[t - off] : 0;
        __syncthreads();
        sh[t] += x;
        __syncthreads();
    }
    int run = partial[b] + sh[t] - s;
    #pragma unroll
    for (int i = 0; i < 4; ++i) {
        if (base + i < N) rp[base + i] = run;
        run += v[i];
    }
    if (b == 0 && t == 0) rp[N] = E;
}

__global__ void k_init_bcur2(const int* __restrict__ rp_m, const int* __restrict__ rp_u,
                             int* __restrict__ bcur_m, int* __restrict__ bcur_u,
                             int NBm, int NBu) {
    int t = threadIdx.x;
    if (t < NBm) bcur_m[t] = rp_m[t << BSHIFT];
    if (t < NBu) bcur_u[t] = rp_u[t << BSHIFT];
}

// LDS-binned bucket scatter: chunk of CHUNK edges -> bucket-grouped (key,val) pairs
__global__ __launch_bounds__(256) void k_bucket_scatter(
    const int* __restrict__ key, const int* __restrict__ val,
    int* __restrict__ bcur, uint2* __restrict__ pairs, int E, int NB)
{
    __shared__ int lcnt[256], lstart[256], gbase[256];
    __shared__ uint2 lpair[CHUNK];
    int tid = threadIdx.x;
    int base = blockIdx.x * CHUNK;
    int kk[EPT], vv[EPT], ofs[EPT];
    #pragma unroll
    for (int i = 0; i < EPT; ++i) {
        int idx = base + i * 256 + tid;
        bool ok = idx < E;
        kk[i] = ok ? key[idx] : -1;
        vv[i] = ok ? val[idx] : 0;
    }
    lcnt[tid] = 0;
    __syncthreads();
    #pragma unroll
    for (int i = 0; i < EPT; ++i)
        if (kk[i] >= 0) ofs[i] = atomicAdd(&lcnt[kk[i] >> BSHIFT], 1);
    __syncthreads();
    int c = lcnt[tid];
    lstart[tid] = c;
    __syncthreads();
    for (int off = 1; off < 256; off <<= 1) {
        int x = (tid >= off) ? lstart[tid - off] : 0;
        __syncthreads();
        lstart[tid] += x;
        __syncthreads();
    }
    lstart[tid] -= c;                       // exclusive (own slot only)
    if (c > 0 && tid < NB) gbase[tid] = atomicAdd(&bcur[tid], c);
    __syncthreads();
    #pragma unroll
    for (int i = 0; i < EPT; ++i)
        if (kk[i] >= 0) {
            int b = kk[i] >> BSHIFT;
            lpair[lstart[b] + ofs[i]] = make_uint2((uint)kk[i], (uint)vv[i]);
        }
    __syncthreads();
    int total = E - base; if (total > CHUNK) total = CHUNK;
    for (int j = tid; j < total; j += 256) {
        uint2 p = lpair[j];
        int b = (int)(p.x >> BSHIFT);
        pairs[gbase[b] + (j - lstart[b])] = p;
    }
}

// block-per-bucket: pairs -> nbr (writes land in a small L2-local window)
__global__ __launch_bounds__(256) void k_bucket_fill(
    const uint2* __restrict__ pairs, const int* __restrict__ rp,
    int* __restrict__ nbr, int N)
{
    __shared__ int lcur[BSIZE];
    int b = blockIdx.x, tid = threadIdx.x;
    int base = b << BSHIFT;
    int end = base + BSIZE; if (end > N) end = N;
    for (int n = tid; n < end - base; n += 256) lcur[n] = rp[base + n];
    __syncthreads();
    int rs = rp[base], re = rp[end];
    for (int j = rs + tid; j < re; j += 256) {
        uint2 p = pairs[j];
        int pos = atomicAdd(&lcur[(int)p.x - base], 1);
        nbr[pos] = (int)p.y;
    }
}

// ---------------- weight fragment packing (5 matrices, one kernel) ----------------
__global__ void k_pack_all(const float* __restrict__ w0lo, const float* __restrict__ w0hi,
                           const float* __restrict__ w1lo, const float* __restrict__ w1hi,
                           const float* __restrict__ w2lo, const float* __restrict__ w2hi,
                           const float* __restrict__ w3lo, const float* __restrict__ w3hi,
                           const float* __restrict__ w4lo, const float* __restrict__ w4hi,
                           ushort* __restrict__ dst) {
    int t = blockIdx.x * blockDim.x + threadIdx.x;   // 40960 threads
    int mid = t >> 13, r = t & 8191;
    const float* lo; const float* hi;
    switch (mid) {
        case 0: lo = w0lo; hi = w0hi; break;
        case 1: lo = w1lo; hi = w1hi; break;
        case 2: lo = w2lo; hi = w2hi; break;
        case 3: lo = w3lo; hi = w3hi; break;
        default: lo = w4lo; hi = w4hi;
    }
    int e = r & 7, lane = (r >> 3) & 63, nn = (r >> 9) & 3, kk = r >> 11;
    int k = (lane >> 4) * 8 + e + 32 * kk;
    int col = (lane & 15) + 16 * nn;
    float v = (k < 64) ? lo[k * 64 + col] : hi[(k - 64) * 64 + col];
    dst[t] = f2bf(v);
}

__global__ void k_init_ss(float* __restrict__ ss_id) {
    int t = threadIdx.x;
    if (t < 64) { ss_id[t] = 1.f; ss_id[64 + t] = 0.f; }
}

// ---------------- segmented mean (half-wave per node, uint loads, fused BN) ----------------
template<int RELU>
__global__ __launch_bounds__(256) void k_reduce_mean(
    const ushort* __restrict__ xsrc, const float* __restrict__ ssx,
    const int* __restrict__ rp, const int* __restrict__ nbr,
    ushort* __restrict__ mean, int N)
{
    int slot = blockIdx.x * 8 + (threadIdx.x >> 5);
    if (slot >= N) return;
    int c = threadIdx.x & 31;
    float sc0 = ssx[2 * c], sc1 = ssx[2 * c + 1];
    float sh0 = ssx[64 + 2 * c], sh1 = ssx[64 + 2 * c + 1];
    const uint* xs = (const uint*)xsrc;
    int s0 = rp[slot], s1 = rp[slot + 1];
    float a0 = 0.f, a1 = 0.f;
    int k = s0;
    for (; k + 4 <= s1; k += 4) {
        int n0 = nbr[k], n1 = nbr[k + 1], n2 = nbr[k + 2], n3 = nbr[k + 3];
        uint u0 = xs[(size_t)n0 * 32 + c], u1 = xs[(size_t)n1 * 32 + c];
        uint u2 = xs[(size_t)n2 * 32 + c], u3 = xs[(size_t)n3 * 32 + c];
        uint uu[4] = {u0, u1, u2, u3};
        #pragma unroll
        for (int i = 0; i < 4; ++i) {
            float f0 = __uint_as_float(uu[i] << 16) * sc0 + sh0;
            float f1 = __uint_as_float(uu[i] & 0xffff0000u) * sc1 + sh1;
            if (RELU) { f0 = fmaxf(f0, 0.f); f1 = fmaxf(f1, 0.f); }
            a0 += f0; a1 += f1;
        }
    }
    for (; k < s1; ++k) {
        uint u = xs[(size_t)nbr[k] * 32 + c];
        float f0 = __uint_as_float(u << 16) * sc0 + sh0;
        float f1 = __uint_as_float(u & 0xffff0000u) * sc1 + sh1;
        if (RELU) { f0 = fmaxf(f0, 0.f); f1 = fmaxf(f1, 0.f); }
        a0 += f0; a1 += f1;
    }
    float inv = (s1 > s0) ? 1.f / (float)(s1 - s0) : 0.f;
    ((uint*)mean)[(size_t)slot * 32 + c] = pack2(a0 * inv, a1 * inv);
}

// BN-apply on a bf16x8 A-fragment (sc/sh point at the 8-col window)
template<int RELU>
__device__ __forceinline__ bf16x8 bn_frag(bf16x8 raw, const float* sc, const float* sh) {
    bf16x8 o;
    #pragma unroll
    for (int e = 0; e < 8; ++e) {
        float f = bf2f(((const ushort*)&raw)[e]);
        f = f * sc[e] + sh[e];
        if (RELU) f = fmaxf(f, 0.f);
        ((ushort*)&o)[e] = f2bf(f);
    }
    return o;
}

// ---------------- MFMA: out = [mean | BN(xdst)] @ Wcat + bias, fused col-stats ----------------
template<int RELU>
__global__ __launch_bounds__(256) void k_sage_mfma(
    const ushort* __restrict__ meanb, const ushort* __restrict__ xdst,
    const float* __restrict__ ssd,
    const ushort* __restrict__ wp, const float* __restrict__ blv,
    ushort* __restrict__ out, float* __restrict__ stats, int N)
{
    __shared__ float lsum[64], lsq[64];
    if (threadIdx.x < 64) { lsum[threadIdx.x] = 0.f; lsq[threadIdx.x] = 0.f; }
    __syncthreads();
    int wave = threadIdx.x >> 6, lane = threadIdx.x & 63;
    int n0 = blockIdx.x * 64 + wave * 16;
    int lrow = lane & 15, lk = lane >> 4;
    int arow = n0 + lrow; if (arow >= N) arow = N - 1;
    const ushort* pm = meanb + (size_t)arow * HD + lk * 8;
    const ushort* px = xdst  + (size_t)arow * HD + lk * 8;
    const bf16x8* wpv = (const bf16x8*)wp + lane;

    bf16x8 b[4][4];
    #pragma unroll
    for (int kk = 0; kk < 4; ++kk)
        #pragma unroll
        for (int nn = 0; nn < 4; ++nn)
            b[kk][nn] = wpv[(kk * 4 + nn) * 64];

    bf16x8 a[4];
    a[0] = *(const bf16x8*)(pm);
    a[1] = *(const bf16x8*)(pm + 32);
    a[2] = bn_frag<RELU>(*(const bf16x8*)(px),      ssd + lk * 8,      ssd + 64 + lk * 8);
    a[3] = bn_frag<RELU>(*(const bf16x8*)(px + 32), ssd + 32 + lk * 8, ssd + 96 + lk * 8);

    f32x4 acc[4];
    #pragma unroll
    for (int nn = 0; nn < 4; ++nn) acc[nn] = (f32x4){0.f, 0.f, 0.f, 0.f};
    #pragma unroll
    for (int kk = 0; kk < 4; ++kk)
        #pragma unroll
        for (int nn = 0; nn < 4; ++nn)
            acc[nn] = __builtin_amdgcn_mfma_f32_16x16x32_bf16(a[kk], b[kk][nn], acc[nn], 0, 0, 0);

    #pragma unroll
    for (int nn = 0; nn < 4; ++nn) {
        float bias = blv[lrow + 16 * nn];
        float s = 0.f, q = 0.f;
        #pragma unroll
        for (int r = 0; r < 4; ++r) {
            int orow = n0 + lk * 4 + r;
            float v = acc[nn][r] + bias;
            bool ok = orow < N;
            if (ok) out[(size_t)orow * HD + lrow + 16 * nn] = f2bf(v);
            float vv = ok ? v : 0.f;
            s += vv; q += vv * vv;
        }
        s += __shfl_xor(s, 16); s += __shfl_xor(s, 32);
        q += __shfl_xor(q, 16); q += __shfl_xor(q, 32);
        if (lk == 0) {
            atomAddF(&lsum[lrow + 16 * nn], s);
            atomAddF(&lsq[lrow + 16 * nn], q);
        }
    }
    __syncthreads();
    if (threadIdx.x < 64) {
        atomAddF(&stats[threadIdx.x], lsum[threadIdx.x]);
        atomAddF(&stats[64 + threadIdx.x], lsq[threadIdx.x]);
    }
}

__global__ void k_bn_finalize(const float* __restrict__ stats,
                              const float* __restrict__ g, const float* __restrict__ b,
                              float* __restrict__ ss, int N)
{
    int j = threadIdx.x;
    if (j < HD) {
        float invN = 1.f / (float)N;
        float mu = stats[j] * invN;
        float var = stats[HD + j] * invN - mu * mu;
        var = var < 0.f ? 0.f : var;
        float sc = g[j] * rsqrtf(var + 1e-5f);
        ss[j] = sc;
        ss[HD + j] = b[j] - mu * sc;
    }
}

// ---------------- classifier (BN both operands, fused) ----------------
__global__ __launch_bounds__(256) void k_cls_mfma(
    const ushort* __restrict__ xu, const float* __restrict__ ssu,
    const ushort* __restrict__ xm, const float* __restrict__ ssm,
    const int* __restrict__ lsrc, const int* __restrict__ ldst,
    const ushort* __restrict__ wp, const float* __restrict__ b1,
    const float* __restrict__ w2, const float* __restrict__ b2,
    float* __restrict__ out, int L)
{
    int wave = threadIdx.x >> 6, lane = threadIdx.x & 63;
    int l0 = blockIdx.x * 64 + wave * 16;
    if (l0 >= L) return;
    int lrow = lane & 15, lk = lane >> 4;
    int li = l0 + lrow; if (li >= L) li = L - 1;
    const ushort* pu = xu + (size_t)lsrc[li] * HD + lk * 8;
    const ushort* pm = xm + (size_t)ldst[li] * HD + lk * 8;
    const bf16x8* wpv = (const bf16x8*)wp + lane;

    bf16x8 a[4];
    a[0] = bn_frag<1>(*(const bf16x8*)(pu),      ssu + lk * 8,      ssu + 64 + lk * 8);
    a[1] = bn_frag<1>(*(const bf16x8*)(pu + 32), ssu + 32 + lk * 8, ssu + 96 + lk * 8);
    a[2] = bn_frag<1>(*(const bf16x8*)(pm),      ssm + lk * 8,      ssm + 64 + lk * 8);
    a[3] = bn_frag<1>(*(const bf16x8*)(pm + 32), ssm + 32 + lk * 8, ssm + 96 + lk * 8);

    f32x4 acc[4];
    #pragma unroll
    for (int nn = 0; nn < 4; ++nn) acc[nn] = (f32x4){0.f, 0.f, 0.f, 0.f};
    #pragma unroll
    for (int kk = 0; kk < 4; ++kk)
        #pragma unroll
        for (int nn = 0; nn < 4; ++nn)
            acc[nn] = __builtin_amdgcn_mfma_f32_16x16x32_bf16(a[kk], wpv[(kk * 4 + nn) * 64], acc[nn], 0, 0, 0);

    float p0 = 0.f, p1 = 0.f, p2 = 0.f, p3 = 0.f;
    #pragma unroll
    for (int nn = 0; nn < 4; ++nn) {
        int cidx = lrow + 16 * nn;
        float bb = b1[cidx], w = w2[cidx];
        p0 += fmaxf(acc[nn][0] + bb, 0.f) * w;
        p1 += fmaxf(acc[nn][1] + bb, 0.f) * w;
        p2 += fmaxf(acc[nn][2] + bb, 0.f) * w;
        p3 += fmaxf(acc[nn][3] + bb, 0.f) * w;
    }
    #pragma unroll
    for (int off = 1; off < 16; off <<= 1) {
        p0 += __shfl_xor(p0, off);
        p1 += __shfl_xor(p1, off);
        p2 += __shfl_xor(p2, off);
        p3 += __shfl_xor(p3, off);
    }
    if (lrow == 0) {
        float bb2 = b2[0];
        int r0 = l0 + lk * 4;
        if (r0 + 0 < L) out[r0 + 0] = p0 + bb2;
        if (r0 + 1 < L) out[r0 + 1] = p1 + bb2;
        if (r0 + 2 < L) out[r0 + 2] = p2 + bb2;
        if (r0 + 3 < L) out[r0 + 3] = p3 + bb2;
    }
}

// ---------------- dense init ----------------

__global__ __launch_bounds__(256) void k_movie_feat(
    const float* __restrict__ mx, const float* __restrict__ W,
    const float* __restrict__ b, const float* __restrict__ memb,
    const int* __restrict__ mids, ushort* __restrict__ xm, int NM, int F)
{
    int m = blockIdx.x * blockDim.x + threadIdx.x;
    if (m >= NM) return;
    const float* xr = mx + (size_t)m * F;
    float acc[HD];
    #pragma unroll
    for (int j = 0; j < HD; ++j) acc[j] = b[j];
    for (int f = 0; f < F; ++f) {
        float v = xr[f];
        #pragma unroll
        for (int j = 0; j < HD; ++j) acc[j] += v * W[f * HD + j];
    }
    int nid = mids[m];
    const float* er = memb + (size_t)nid * HD;
    uint* o = (uint*)(xm + (size_t)m * HD);
    #pragma unroll
    for (int j = 0; j < HD; j += 2)
        o[j >> 1] = pack2(acc[j] + er[j], acc[j + 1] + er[j + 1]);
}

__global__ __launch_bounds__(256) void k_gather_rows(
    const float* __restrict__ src, const int* __restrict__ idx,
    ushort* __restrict__ dst, int N)
{
    int t = blockIdx.x * blockDim.x + threadIdx.x;
    int total = N * HD;
    int stride = gridDim.x * blockDim.x;
    for (; t < total; t += stride) {
        int i = t >> 6, h = t & 63;
        dst[t] = f2bf(src[(size_t)idx[i] * HD + h]);
    }
}

extern "C" void kernel_launch(void* const* d_in, const int* in_sizes, int n_in,
                              void* d_out, int out_size, void* d_ws, size_t ws_size,
                              hipStream_t stream) {
    (void)n_in; (void)ws_size;
    const int NU = in_sizes[1] / HD;
    const int NM = in_sizes[2] / HD;
    const int F  = in_sizes[0] / NM;
    const int E  = in_sizes[31];
    const int L  = out_size;
    const int NBm = (NM + BSIZE - 1) >> BSHIFT;
    const int NBu = (NU + BSIZE - 1) >> BSHIFT;

    int iL0RA, iL0RE, iL1RA, iL1RE, iBN0U, iBN0M, iBN1U, iBN1M;
    if (in_sizes[11] == HD) {          // setup-dict order
        iL0RA = 5; iL0RE = 8; iBN0U = 11; iBN0M = 13;
        iL1RA = 15; iL1RE = 18; iBN1U = 21; iBN1M = 23;
    } else {                           // reference-signature order
        iL0RA = 5; iL0RE = 8; iL1RA = 11; iL1RE = 14;
        iBN0U = 17; iBN0M = 19; iBN1U = 21; iBN1M = 23;
    }
    const float* movie_x   = (const float*)d_in[0];
    const float* user_emb  = (const float*)d_in[1];
    const float* movie_emb = (const float*)d_in[2];
    const float* mlw       = (const float*)d_in[3];
    const float* mlb       = (const float*)d_in[4];
    const float* cls_w1    = (const float*)d_in[25];
    const float* cls_b1    = (const float*)d_in[26];
    const float* cls_w2    = (const float*)d_in[27];
    const float* cls_b2    = (const float*)d_in[28];
    const int* user_node_id  = (const int*)d_in[29];
    const int* movie_node_id = (const int*)d_in[30];
    const int* rates_src   = (const int*)d_in[31];
    const int* rates_dst   = (const int*)d_in[32];
    const int* label_src   = (const int*)d_in[33];
    const int* label_dst   = (const int*)d_in[34];

    // ---- workspace ----
    char* wsb = (char*)d_ws;
    auto alloc = [&](size_t bytes) { char* p = wsb; wsb += (bytes + 255) & ~(size_t)255; return p; };
    int nmax = NU > NM ? NU : NM;
    ushort* xu_a = (ushort*)alloc((size_t)NU * HD * 2);
    ushort* xu_b = (ushort*)alloc((size_t)NU * HD * 2);
    ushort* xm_a = (ushort*)alloc((size_t)NM * HD * 2);
    ushort* xm_b = (ushort*)alloc((size_t)NM * HD * 2);
    ushort* meanb = (ushort*)alloc((size_t)nmax * HD * 2);
    ushort* wp_all = (ushort*)alloc(5 * 8192 * 2);
    int* rp_m = (int*)alloc((size_t)(NM + 1) * 4);
    int* rp_u = (int*)alloc((size_t)(NU + 1) * 4);
    int* nbr_m = (int*)alloc((size_t)E * 4);
    int* nbr_u = (int*)alloc((size_t)E * 4);
    uint2* pairs = (uint2*)alloc((size_t)E * 8);
    int* bcur_m = (int*)alloc(256 * 4);
    int* bcur_u = (int*)alloc(256 * 4);
    int* partial = (int*)alloc(256 * 4);
    char* zr = alloc((size_t)(NM + NU) * 4 + 2048);   // zeroed region
    int* cnt_m = (int*)zr;
    int* cnt_u = cnt_m + NM;
    float* statsAll = (float*)(cnt_u + NU);           // 4 x 128 floats
    float* ss_id = (float*)alloc(128 * 4);
    float* ss_u0 = (float*)alloc(128 * 4);
    float* ss_m0 = (float*)alloc(128 * 4);
    float* ss_u1 = (float*)alloc(128 * 4);
    float* ss_m1 = (float*)alloc(128 * 4);

    ushort* wp0 = wp_all;              // l0 rev
    ushort* wp1 = wp_all + 8192;       // l0 rates
    ushort* wp2 = wp_all + 16384;      // l1 rev
    ushort* wp3 = wp_all + 24576;      // l1 rates
    ushort* wpc = wp_all + 32768;      // classifier
    float* st0 = statsAll, *st1 = statsAll + 128, *st2 = statsAll + 256, *st3 = statsAll + 384;

    const int egrid = (E + 255) / 256;
    const int sgrid = (E + CHUNK - 1) / CHUNK;

    hipMemsetAsync(zr, 0, (size_t)(NM + NU) * 4 + 2048, stream);
    k_init_ss<<<1, 64, 0, stream>>>(ss_id);
    k_pack_all<<<160, 256, 0, stream>>>(
        (const float*)d_in[iL0RE + 0], (const float*)d_in[iL0RE + 2],
        (const float*)d_in[iL0RA + 0], (const float*)d_in[iL0RA + 2],
        (const float*)d_in[iL1RE + 0], (const float*)d_in[iL1RE + 2],
        (const float*)d_in[iL1RA + 0], (const float*)d_in[iL1RA + 2],
        cls_w1, cls_w1 + 64 * 64, wp_all);

    // ---- CSR build ----
    k_hist2<<<egrid, 256, 0, stream>>>(rates_src, rates_dst, cnt_u, cnt_m, E);
    {
        int nb = (NM + SCAN_CH - 1) / SCAN_CH;
        k_scan_a<<<nb, 256, 0, stream>>>(cnt_m, partial, NM);
        k_scan_b<<<1, 256, 0, stream>>>(partial, nb);
        k_scan_c<<<nb, 256, 0, stream>>>(cnt_m, partial, rp_m, NM, E);
    }
    {
        int nb = (NU + SCAN_CH - 1) / SCAN_CH;
        k_scan_a<<<nb, 256, 0, stream>>>(cnt_u, partial, NU);
        k_scan_b<<<1, 256, 0, stream>>>(partial, nb);
        k_scan_c<<<nb, 256, 0, stream>>>(cnt_u, partial, rp_u, NU, E);
    }
    k_init_bcur2<<<1, 256, 0, stream>>>(rp_m, rp_u, bcur_m, bcur_u, NBm, NBu);
    // movie CSR (key=dst, val=src), then user CSR (key=src, val=dst); pairs buffer reused
    k_bucket_scatter<<<sgrid, 256, 0, stream>>>(rates_dst, rates_src, bcur_m, pairs, E, NBm);
    k_bucket_fill<<<NBm, 256, 0, stream>>>(pairs, rp_m, nbr_m, NM);
    k_bucket_scatter<<<sgrid, 256, 0, stream>>>(rates_src, rates_dst, bcur_u, pairs, E, NBu);
    k_bucket_fill<<<NBu, 256, 0, stream>>>(pairs, rp_u, nbr_u, NU);

    // ---- init node features ----
    k_movie_feat<<<(NM + 255) / 256, 256, 0, stream>>>(movie_x, mlw, mlb, movie_emb, movie_node_id, xm_a, NM, F);
    k_gather_rows<<<2048, 256, 0, stream>>>(user_emb, user_node_id, xu_a, NU);

    // ---- stage 0: user <- rev(movie) ----
    k_reduce_mean<0><<<(NU + 7) / 8, 256, 0, stream>>>(xm_a, ss_id, rp_u, nbr_u, meanb, NU);
    k_sage_mfma<0><<<(NU + 63) / 64, 256, 0, stream>>>(meanb, xu_a, ss_id, wp0,
        (const float*)d_in[iL0RE + 1], xu_b, st0, NU);
    k_bn_finalize<<<1, 64, 0, stream>>>(st0, (const float*)d_in[iBN0U], (const float*)d_in[iBN0U + 1], ss_u0, NU);
    // ---- stage 1: movie <- rates(user) ----
    k_reduce_mean<0><<<(NM + 7) / 8, 256, 0, stream>>>(xu_a, ss_id, rp_m, nbr_m, meanb, NM);
    k_sage_mfma<0><<<(NM + 63) / 64, 256, 0, stream>>>(meanb, xm_a, ss_id, wp1,
        (const float*)d_in[iL0RA + 1], xm_b, st1, NM);
    k_bn_finalize<<<1, 64, 0, stream>>>(st1, (const float*)d_in[iBN0M], (const float*)d_in[iBN0M + 1], ss_m0, NM);
    // ---- stage 2: user layer 1 ----
    k_reduce_mean<1><<<(NU + 7) / 8, 256, 0, stream>>>(xm_b, ss_m0, rp_u, nbr_u, meanb, NU);
    k_sage_mfma<1><<<(NU + 63) / 64, 256, 0, stream>>>(meanb, xu_b, ss_u0, wp2,
        (const float*)d_in[iL1RE + 1], xu_a, st2, NU);
    k_bn_finalize<<<1, 64, 0, stream>>>(st2, (const float*)d_in[iBN1U], (const float*)d_in[iBN1U + 1], ss_u1, NU);
    // ---- stage 3: movie layer 1 ----
    k_reduce_mean<1><<<(NM + 7) / 8, 256, 0, stream>>>(xu_b, ss_u0, rp_m, nbr_m, meanb, NM);
    k_sage_mfma<1><<<(NM + 63) / 64, 256, 0, stream>>>(meanb, xm_b, ss_m0, wp3,
        (const float*)d_in[iL1RA + 1], xm_a, st3, NM);
    k_bn_finalize<<<1, 64, 0, stream>>>(st3, (const float*)d_in[iBN1M], (const float*)d_in[iBN1M + 1], ss_m1, NM);

    // ---- classifier ----
    k_cls_mfma<<<(L + 63) / 64, 256, 0, stream>>>(xu_a, ss_u1, xm_a, ss_m1,
        label_src, label_dst, wpc, cls_b1, cls_w2, cls_b2, (float*)d_out, L);
}

// Round 5
// 416.891 us; speedup vs baseline: 4.4946x; 1.1661x over previous
//
#include <hip/hip_runtime.h>
#include <hip/hip_bf16.h>
#include <stdint.h>

#define HD 64
#define CHUNK 4096
#define EPT 16
#define BSHIFT 9
#define BSIZE 512
#define FCAP 12288
#define VMASK 0x7fffffu   // low 23 bits = value; high 9 bits = node-within-bucket

typedef __bf16 bf16x8 __attribute__((ext_vector_type(8)));
typedef float f32x4 __attribute__((ext_vector_type(4)));

__device__ __forceinline__ void atomAddF(float* p, float v) { unsafeAtomicAdd(p, v); }
__device__ __forceinline__ ushort f2bf(float v) {
    __hip_bfloat16 h = __float2bfloat16(v);
    return *(ushort*)&h;
}
__device__ __forceinline__ float bf2f(ushort u) {
    return __uint_as_float(((uint)u) << 16);
}
__device__ __forceinline__ uint pack2(float a, float b) {
    return (uint)f2bf(a) | ((uint)f2bf(b) << 16);
}

// ---------------- CSR build (bucket-local, no global fine histogram) ----------------

// Pass A: bucket-level histogram for both directions, LDS-privatized
__global__ __launch_bounds__(256) void k_bucket_hist(
    const int* __restrict__ src, const int* __restrict__ dst,
    int* __restrict__ bk_u, int* __restrict__ bk_m, int E)
{
    __shared__ int hu[256], hm[256];
    int tid = threadIdx.x;
    hu[tid] = 0; hm[tid] = 0;
    __syncthreads();
    int t = blockIdx.x * 256 + tid;
    int stride = gridDim.x * 256;
    for (; t < E; t += stride) {
        atomicAdd(&hu[src[t] >> BSHIFT], 1);
        atomicAdd(&hm[dst[t] >> BSHIFT], 1);
    }
    __syncthreads();
    if (hu[tid]) atomicAdd(&bk_u[tid], hu[tid]);
    if (hm[tid]) atomicAdd(&bk_m[tid], hm[tid]);
}

// Pass B: exclusive scan of both bucket-count arrays (single block)
__global__ void k_bucket_scan(const int* __restrict__ bk_u, const int* __restrict__ bk_m,
                              int* __restrict__ bkrp_u, int* __restrict__ bkrp_m,
                              int* __restrict__ bcur_u, int* __restrict__ bcur_m,
                              int NBu, int NBm, int E)
{
    __shared__ int sh[256];
    int t = threadIdx.x;
    int v = (t < NBu) ? bk_u[t] : 0;
    sh[t] = v; __syncthreads();
    for (int off = 1; off < 256; off <<= 1) {
        int x = (t >= off) ? sh[t - off] : 0;
        __syncthreads(); sh[t] += x; __syncthreads();
    }
    int excl = sh[t] - v;
    if (t < NBu) { bkrp_u[t] = excl; bcur_u[t] = excl; }
    if (t == NBu) bkrp_u[t] = E;
    __syncthreads();
    v = (t < NBm) ? bk_m[t] : 0;
    sh[t] = v; __syncthreads();
    for (int off = 1; off < 256; off <<= 1) {
        int x = (t >= off) ? sh[t - off] : 0;
        __syncthreads(); sh[t] += x; __syncthreads();
    }
    excl = sh[t] - v;
    if (t < NBm) { bkrp_m[t] = excl; bcur_m[t] = excl; }
    if (t == NBm) bkrp_m[t] = E;
}

// Pass C: LDS-binned bucket scatter -> bucket-grouped packed pairs (rel<<23 | val)
__global__ __launch_bounds__(256) void k_bucket_scatter(
    const int* __restrict__ key, const int* __restrict__ val,
    int* __restrict__ bcur, uint* __restrict__ pairs, int E, int NB)
{
    __shared__ int lcnt[256], lstart[256], gbase[256];
    __shared__ uint2 lpair[CHUNK];
    int tid = threadIdx.x;
    int base = blockIdx.x * CHUNK;
    int kk[EPT], vv[EPT], ofs[EPT];
    #pragma unroll
    for (int i = 0; i < EPT; ++i) {
        int idx = base + i * 256 + tid;
        bool ok = idx < E;
        kk[i] = ok ? key[idx] : -1;
        vv[i] = ok ? val[idx] : 0;
    }
    lcnt[tid] = 0;
    __syncthreads();
    #pragma unroll
    for (int i = 0; i < EPT; ++i)
        if (kk[i] >= 0) ofs[i] = atomicAdd(&lcnt[kk[i] >> BSHIFT], 1);
    __syncthreads();
    int c = lcnt[tid];
    lstart[tid] = c;
    __syncthreads();
    for (int off = 1; off < 256; off <<= 1) {
        int x = (tid >= off) ? lstart[tid - off] : 0;
        __syncthreads(); lstart[tid] += x; __syncthreads();
    }
    lstart[tid] -= c;
    if (c > 0 && tid < NB) gbase[tid] = atomicAdd(&bcur[tid], c);
    __syncthreads();
    #pragma unroll
    for (int i = 0; i < EPT; ++i)
        if (kk[i] >= 0) {
            int b = kk[i] >> BSHIFT;
            lpair[lstart[b] + ofs[i]] = make_uint2((uint)kk[i], (uint)vv[i]);
        }
    __syncthreads();
    int total = E - base; if (total > CHUNK) total = CHUNK;
    for (int j = tid; j < total; j += 256) {
        uint2 p = lpair[j];
        int b = (int)(p.x >> BSHIFT);
        pairs[gbase[b] + (j - lstart[b])] = ((p.x & (BSIZE - 1)) << 23) | p.y;
    }
}

// Pass D: per-bucket fine histogram + scan + rp emit + nbr placement, all in LDS
__global__ __launch_bounds__(256) void k_bucket_finalize(
    const uint* __restrict__ pairs, const int* __restrict__ bkrp,
    int* __restrict__ rp, int* __restrict__ nbr, int N, int E)
{
    __shared__ int lcnt[BSIZE];
    __shared__ int lsc[256];
    __shared__ uint lp[FCAP];
    int b = blockIdx.x, tid = threadIdx.x;
    int base = b << BSHIFT;
    int rs = bkrp[b], re = bkrp[b + 1];
    int cnt = re - rs;
    bool staged = cnt <= FCAP;
    lcnt[tid] = 0; lcnt[tid + 256] = 0;
    __syncthreads();
    if (staged) {
        for (int j = tid; j < cnt; j += 256) {
            uint p = pairs[rs + j];
            lp[j] = p;
            atomicAdd(&lcnt[p >> 23], 1);
        }
    } else {
        for (int j = rs + tid; j < re; j += 256)
            atomicAdd(&lcnt[pairs[j] >> 23], 1);
    }
    __syncthreads();
    int c0 = lcnt[2 * tid], c1 = lcnt[2 * tid + 1];
    int s = c0 + c1;
    lsc[tid] = s;
    __syncthreads();
    for (int off = 1; off < 256; off <<= 1) {
        int x = (tid >= off) ? lsc[tid - off] : 0;
        __syncthreads(); lsc[tid] += x; __syncthreads();
    }
    int excl = lsc[tid] - s;
    int nbn = N - base; if (nbn > BSIZE) nbn = BSIZE;
    if (2 * tid < nbn)     rp[base + 2 * tid]     = rs + excl;
    if (2 * tid + 1 < nbn) rp[base + 2 * tid + 1] = rs + excl + c0;
    if (b == gridDim.x - 1 && tid == 0) rp[N] = E;
    lcnt[2 * tid] = excl;
    lcnt[2 * tid + 1] = excl + c0;
    __syncthreads();
    if (staged) {
        for (int j = tid; j < cnt; j += 256) {
            uint p = lp[j];
            int pos = rs + atomicAdd(&lcnt[p >> 23], 1);
            nbr[pos] = (int)(p & VMASK);
        }
    } else {
        for (int j = rs + tid; j < re; j += 256) {
            uint p = pairs[j];
            int pos = rs + atomicAdd(&lcnt[p >> 23], 1);
            nbr[pos] = (int)(p & VMASK);
        }
    }
}

// ---------------- weight fragment packing (5 matrices, one kernel) ----------------
__global__ void k_pack_all(const float* __restrict__ w0lo, const float* __restrict__ w0hi,
                           const float* __restrict__ w1lo, const float* __restrict__ w1hi,
                           const float* __restrict__ w2lo, const float* __restrict__ w2hi,
                           const float* __restrict__ w3lo, const float* __restrict__ w3hi,
                           const float* __restrict__ w4lo, const float* __restrict__ w4hi,
                           ushort* __restrict__ dst) {
    int t = blockIdx.x * blockDim.x + threadIdx.x;   // 40960 threads
    int mid = t >> 13, r = t & 8191;
    const float* lo; const float* hi;
    switch (mid) {
        case 0: lo = w0lo; hi = w0hi; break;
        case 1: lo = w1lo; hi = w1hi; break;
        case 2: lo = w2lo; hi = w2hi; break;
        case 3: lo = w3lo; hi = w3hi; break;
        default: lo = w4lo; hi = w4hi;
    }
    int e = r & 7, lane = (r >> 3) & 63, nn = (r >> 9) & 3, kk = r >> 11;
    int k = (lane >> 4) * 8 + e + 32 * kk;
    int col = (lane & 15) + 16 * nn;
    float v = (k < 64) ? lo[k * 64 + col] : hi[(k - 64) * 64 + col];
    dst[t] = f2bf(v);
}

__global__ void k_init_ss(float* __restrict__ ss_id) {
    int t = threadIdx.x;
    if (t < 64) { ss_id[t] = 1.f; ss_id[64 + t] = 0.f; }
}

// ---------------- segmented mean (half-wave per node, uint loads, fused BN) ----------------
template<int RELU>
__global__ __launch_bounds__(256) void k_reduce_mean(
    const ushort* __restrict__ xsrc, const float* __restrict__ ssx,
    const int* __restrict__ rp, const int* __restrict__ nbr,
    ushort* __restrict__ mean, int N)
{
    int slot = blockIdx.x * 8 + (threadIdx.x >> 5);
    if (slot >= N) return;
    int c = threadIdx.x & 31;
    float sc0 = ssx[2 * c], sc1 = ssx[2 * c + 1];
    float sh0 = ssx[64 + 2 * c], sh1 = ssx[64 + 2 * c + 1];
    const uint* xs = (const uint*)xsrc;
    int s0 = rp[slot], s1 = rp[slot + 1];
    float a0 = 0.f, a1 = 0.f;
    int k = s0;
    for (; k + 4 <= s1; k += 4) {
        int n0 = nbr[k], n1 = nbr[k + 1], n2 = nbr[k + 2], n3 = nbr[k + 3];
        uint u0 = xs[(size_t)n0 * 32 + c], u1 = xs[(size_t)n1 * 32 + c];
        uint u2 = xs[(size_t)n2 * 32 + c], u3 = xs[(size_t)n3 * 32 + c];
        uint uu[4] = {u0, u1, u2, u3};
        #pragma unroll
        for (int i = 0; i < 4; ++i) {
            float f0 = __uint_as_float(uu[i] << 16) * sc0 + sh0;
            float f1 = __uint_as_float(uu[i] & 0xffff0000u) * sc1 + sh1;
            if (RELU) { f0 = fmaxf(f0, 0.f); f1 = fmaxf(f1, 0.f); }
            a0 += f0; a1 += f1;
        }
    }
    for (; k < s1; ++k) {
        uint u = xs[(size_t)nbr[k] * 32 + c];
        float f0 = __uint_as_float(u << 16) * sc0 + sh0;
        float f1 = __uint_as_float(u & 0xffff0000u) * sc1 + sh1;
        if (RELU) { f0 = fmaxf(f0, 0.f); f1 = fmaxf(f1, 0.f); }
        a0 += f0; a1 += f1;
    }
    float inv = (s1 > s0) ? 1.f / (float)(s1 - s0) : 0.f;
    ((uint*)mean)[(size_t)slot * 32 + c] = pack2(a0 * inv, a1 * inv);
}

// BN-apply on a bf16x8 A-fragment (sc/sh point at the 8-col window)
template<int RELU>
__device__ __forceinline__ bf16x8 bn_frag(bf16x8 raw, const float* sc, const float* sh) {
    bf16x8 o;
    #pragma unroll
    for (int e = 0; e < 8; ++e) {
        float f = bf2f(((const ushort*)&raw)[e]);
        f = f * sc[e] + sh[e];
        if (RELU) f = fmaxf(f, 0.f);
        ((ushort*)&o)[e] = f2bf(f);
    }
    return o;
}

// ---------------- MFMA: out = [mean | BN(xdst)] @ Wcat + bias, fused col-stats ----------------
template<int RELU>
__global__ __launch_bounds__(256) void k_sage_mfma(
    const ushort* __restrict__ meanb, const ushort* __restrict__ xdst,
    const float* __restrict__ ssd,
    const ushort* __restrict__ wp, const float* __restrict__ blv,
    ushort* __restrict__ out, float* __restrict__ stats, int N)
{
    __shared__ float lsum[64], lsq[64];
    if (threadIdx.x < 64) { lsum[threadIdx.x] = 0.f; lsq[threadIdx.x] = 0.f; }
    __syncthreads();
    int wave = threadIdx.x >> 6, lane = threadIdx.x & 63;
    int n0 = blockIdx.x * 64 + wave * 16;
    int lrow = lane & 15, lk = lane >> 4;
    int arow = n0 + lrow; if (arow >= N) arow = N - 1;
    const ushort* pm = meanb + (size_t)arow * HD + lk * 8;
    const ushort* px = xdst  + (size_t)arow * HD + lk * 8;
    const bf16x8* wpv = (const bf16x8*)wp + lane;

    bf16x8 b[4][4];
    #pragma unroll
    for (int kk = 0; kk < 4; ++kk)
        #pragma unroll
        for (int nn = 0; nn < 4; ++nn)
            b[kk][nn] = wpv[(kk * 4 + nn) * 64];

    bf16x8 a[4];
    a[0] = *(const bf16x8*)(pm);
    a[1] = *(const bf16x8*)(pm + 32);
    a[2] = bn_frag<RELU>(*(const bf16x8*)(px),      ssd + lk * 8,      ssd + 64 + lk * 8);
    a[3] = bn_frag<RELU>(*(const bf16x8*)(px + 32), ssd + 32 + lk * 8, ssd + 96 + lk * 8);

    f32x4 acc[4];
    #pragma unroll
    for (int nn = 0; nn < 4; ++nn) acc[nn] = (f32x4){0.f, 0.f, 0.f, 0.f};
    #pragma unroll
    for (int kk = 0; kk < 4; ++kk)
        #pragma unroll
        for (int nn = 0; nn < 4; ++nn)
            acc[nn] = __builtin_amdgcn_mfma_f32_16x16x32_bf16(a[kk], b[kk][nn], acc[nn], 0, 0, 0);

    #pragma unroll
    for (int nn = 0; nn < 4; ++nn) {
        float bias = blv[lrow + 16 * nn];
        float s = 0.f, q = 0.f;
        #pragma unroll
        for (int r = 0; r < 4; ++r) {
            int orow = n0 + lk * 4 + r;
            float v = acc[nn][r] + bias;
            bool ok = orow < N;
            if (ok) out[(size_t)orow * HD + lrow + 16 * nn] = f2bf(v);
            float vv = ok ? v : 0.f;
            s += vv; q += vv * vv;
        }
        s += __shfl_xor(s, 16); s += __shfl_xor(s, 32);
        q += __shfl_xor(q, 16); q += __shfl_xor(q, 32);
        if (lk == 0) {
            atomAddF(&lsum[lrow + 16 * nn], s);
            atomAddF(&lsq[lrow + 16 * nn], q);
        }
    }
    __syncthreads();
    if (threadIdx.x < 64) {
        atomAddF(&stats[threadIdx.x], lsum[threadIdx.x]);
        atomAddF(&stats[64 + threadIdx.x], lsq[threadIdx.x]);
    }
}

__global__ void k_bn_finalize(const float* __restrict__ stats,
                              const float* __restrict__ g, const float* __restrict__ b,
                              float* __restrict__ ss, int N)
{
    int j = threadIdx.x;
    if (j < HD) {
        float invN = 1.f / (float)N;
        float mu = stats[j] * invN;
        float var = stats[HD + j] * invN - mu * mu;
        var = var < 0.f ? 0.f : var;
        float sc = g[j] * rsqrtf(var + 1e-5f);
        ss[j] = sc;
        ss[HD + j] = b[j] - mu * sc;
    }
}

// ---------------- classifier (BN both operands, fused) ----------------
__global__ __launch_bounds__(256) void k_cls_mfma(
    const ushort* __restrict__ xu, const float* __restrict__ ssu,
    const ushort* __restrict__ xm, const float* __restrict__ ssm,
    const int* __restrict__ lsrc, const int* __restrict__ ldst,
    const ushort* __restrict__ wp, const float* __restrict__ b1,
    const float* __restrict__ w2, const float* __restrict__ b2,
    float* __restrict__ out, int L)
{
    int wave = threadIdx.x >> 6, lane = threadIdx.x & 63;
    int l0 = blockIdx.x * 64 + wave * 16;
    if (l0 >= L) return;
    int lrow = lane & 15, lk = lane >> 4;
    int li = l0 + lrow; if (li >= L) li = L - 1;
    const ushort* pu = xu + (size_t)lsrc[li] * HD + lk * 8;
    const ushort* pm = xm + (size_t)ldst[li] * HD + lk * 8;
    const bf16x8* wpv = (const bf16x8*)wp + lane;

    bf16x8 a[4];
    a[0] = bn_frag<1>(*(const bf16x8*)(pu),      ssu + lk * 8,      ssu + 64 + lk * 8);
    a[1] = bn_frag<1>(*(const bf16x8*)(pu + 32), ssu + 32 + lk * 8, ssu + 96 + lk * 8);
    a[2] = bn_frag<1>(*(const bf16x8*)(pm),      ssm + lk * 8,      ssm + 64 + lk * 8);
    a[3] = bn_frag<1>(*(const bf16x8*)(pm + 32), ssm + 32 + lk * 8, ssm + 96 + lk * 8);

    f32x4 acc[4];
    #pragma unroll
    for (int nn = 0; nn < 4; ++nn) acc[nn] = (f32x4){0.f, 0.f, 0.f, 0.f};
    #pragma unroll
    for (int kk = 0; kk < 4; ++kk)
        #pragma unroll
        for (int nn = 0; nn < 4; ++nn)
            acc[nn] = __builtin_amdgcn_mfma_f32_16x16x32_bf16(a[kk], wpv[(kk * 4 + nn) * 64], acc[nn], 0, 0, 0);

    float p0 = 0.f, p1 = 0.f, p2 = 0.f, p3 = 0.f;
    #pragma unroll
    for (int nn = 0; nn < 4; ++nn) {
        int cidx = lrow + 16 * nn;
        float bb = b1[cidx], w = w2[cidx];
        p0 += fmaxf(acc[nn][0] + bb, 0.f) * w;
        p1 += fmaxf(acc[nn][1] + bb, 0.f) * w;
        p2 += fmaxf(acc[nn][2] + bb, 0.f) * w;
        p3 += fmaxf(acc[nn][3] + bb, 0.f) * w;
    }
    #pragma unroll
    for (int off = 1; off < 16; off <<= 1) {
        p0 += __shfl_xor(p0, off);
        p1 += __shfl_xor(p1, off);
        p2 += __shfl_xor(p2, off);
        p3 += __shfl_xor(p3, off);
    }
    if (lrow == 0) {
        float bb2 = b2[0];
        int r0 = l0 + lk * 4;
        if (r0 + 0 < L) out[r0 + 0] = p0 + bb2;
        if (r0 + 1 < L) out[r0 + 1] = p1 + bb2;
        if (r0 + 2 < L) out[r0 + 2] = p2 + bb2;
        if (r0 + 3 < L) out[r0 + 3] = p3 + bb2;
    }
}

// ---------------- dense init ----------------

__global__ __launch_bounds__(256) void k_movie_feat(
    const float* __restrict__ mx, const float* __restrict__ W,
    const float* __restrict__ b, const float* __restrict__ memb,
    const int* __restrict__ mids, ushort* __restrict__ xm, int NM, int F)
{
    int m = blockIdx.x * blockDim.x + threadIdx.x;
    if (m >= NM) return;
    const float* xr = mx + (size_t)m * F;
    float acc[HD];
    #pragma unroll
    for (int j = 0; j < HD; ++j) acc[j] = b[j];
    for (int f = 0; f < F; ++f) {
        float v = xr[f];
        #pragma unroll
        for (int j = 0; j < HD; ++j) acc[j] += v * W[f * HD + j];
    }
    int nid = mids[m];
    const float* er = memb + (size_t)nid * HD;
    uint* o = (uint*)(xm + (size_t)m * HD);
    #pragma unroll
    for (int j = 0; j < HD; j += 2)
        o[j >> 1] = pack2(acc[j] + er[j], acc[j + 1] + er[j + 1]);
}

__global__ __launch_bounds__(256) void k_gather_rows(
    const float* __restrict__ src, const int* __restrict__ idx,
    ushort* __restrict__ dst, int N)
{
    int t = blockIdx.x * blockDim.x + threadIdx.x;
    int total = N * HD;
    int stride = gridDim.x * blockDim.x;
    for (; t < total; t += stride) {
        int i = t >> 6, h = t & 63;
        dst[t] = f2bf(src[(size_t)idx[i] * HD + h]);
    }
}

extern "C" void kernel_launch(void* const* d_in, const int* in_sizes, int n_in,
                              void* d_out, int out_size, void* d_ws, size_t ws_size,
                              hipStream_t stream) {
    (void)n_in; (void)ws_size;
    const int NU = in_sizes[1] / HD;
    const int NM = in_sizes[2] / HD;
    const int F  = in_sizes[0] / NM;
    const int E  = in_sizes[31];
    const int L  = out_size;
    const int NBm = (NM + BSIZE - 1) >> BSHIFT;
    const int NBu = (NU + BSIZE - 1) >> BSHIFT;

    int iL0RA, iL0RE, iL1RA, iL1RE, iBN0U, iBN0M, iBN1U, iBN1M;
    if (in_sizes[11] == HD) {          // setup-dict order
        iL0RA = 5; iL0RE = 8; iBN0U = 11; iBN0M = 13;
        iL1RA = 15; iL1RE = 18; iBN1U = 21; iBN1M = 23;
    } else {                           // reference-signature order
        iL0RA = 5; iL0RE = 8; iL1RA = 11; iL1RE = 14;
        iBN0U = 17; iBN0M = 19; iBN1U = 21; iBN1M = 23;
    }
    const float* movie_x   = (const float*)d_in[0];
    const float* user_emb  = (const float*)d_in[1];
    const float* movie_emb = (const float*)d_in[2];
    const float* mlw       = (const float*)d_in[3];
    const float* mlb       = (const float*)d_in[4];
    const float* cls_w1    = (const float*)d_in[25];
    const float* cls_b1    = (const float*)d_in[26];
    const float* cls_w2    = (const float*)d_in[27];
    const float* cls_b2    = (const float*)d_in[28];
    const int* user_node_id  = (const int*)d_in[29];
    const int* movie_node_id = (const int*)d_in[30];
    const int* rates_src   = (const int*)d_in[31];
    const int* rates_dst   = (const int*)d_in[32];
    const int* label_src   = (const int*)d_in[33];
    const int* label_dst   = (const int*)d_in[34];

    // ---- workspace ----
    char* wsb = (char*)d_ws;
    auto alloc = [&](size_t bytes) { char* p = wsb; wsb += (bytes + 255) & ~(size_t)255; return p; };
    int nmax = NU > NM ? NU : NM;
    ushort* xu_a = (ushort*)alloc((size_t)NU * HD * 2);
    ushort* xu_b = (ushort*)alloc((size_t)NU * HD * 2);
    ushort* xm_a = (ushort*)alloc((size_t)NM * HD * 2);
    ushort* xm_b = (ushort*)alloc((size_t)NM * HD * 2);
    ushort* meanb = (ushort*)alloc((size_t)nmax * HD * 2);
    ushort* wp_all = (ushort*)alloc(5 * 8192 * 2);
    int* rp_m = (int*)alloc((size_t)(NM + 1) * 4);
    int* rp_u = (int*)alloc((size_t)(NU + 1) * 4);
    int* nbr_m = (int*)alloc((size_t)E * 4);
    int* nbr_u = (int*)alloc((size_t)E * 4);
    uint* pairs = (uint*)alloc((size_t)E * 4);
    int* bkrp_m = (int*)alloc(257 * 4);
    int* bkrp_u = (int*)alloc(257 * 4);
    int* bcur_m = (int*)alloc(256 * 4);
    int* bcur_u = (int*)alloc(256 * 4);
    char* zr = alloc(2 * 256 * 4 + 4 * 128 * 4);     // zeroed: bk counts + stats
    int* bk_u = (int*)zr;
    int* bk_m = bk_u + 256;
    float* statsAll = (float*)(bk_m + 256);          // 4 x 128 floats
    float* ss_id = (float*)alloc(128 * 4);
    float* ss_u0 = (float*)alloc(128 * 4);
    float* ss_m0 = (float*)alloc(128 * 4);
    float* ss_u1 = (float*)alloc(128 * 4);
    float* ss_m1 = (float*)alloc(128 * 4);

    ushort* wp0 = wp_all;              // l0 rev
    ushort* wp1 = wp_all + 8192;       // l0 rates
    ushort* wp2 = wp_all + 16384;      // l1 rev
    ushort* wp3 = wp_all + 24576;      // l1 rates
    ushort* wpc = wp_all + 32768;      // classifier
    float* st0 = statsAll, *st1 = statsAll + 128, *st2 = statsAll + 256, *st3 = statsAll + 384;

    const int sgrid = (E + CHUNK - 1) / CHUNK;

    hipMemsetAsync(zr, 0, 2 * 256 * 4 + 4 * 128 * 4, stream);
    k_init_ss<<<1, 64, 0, stream>>>(ss_id);
    k_pack_all<<<160, 256, 0, stream>>>(
        (const float*)d_in[iL0RE + 0], (const float*)d_in[iL0RE + 2],
        (const float*)d_in[iL0RA + 0], (const float*)d_in[iL0RA + 2],
        (const float*)d_in[iL1RE + 0], (const float*)d_in[iL1RE + 2],
        (const float*)d_in[iL1RA + 0], (const float*)d_in[iL1RA + 2],
        cls_w1, cls_w1 + 64 * 64, wp_all);

    // ---- CSR build (bucket-local) ----
    k_bucket_hist<<<1024, 256, 0, stream>>>(rates_src, rates_dst, bk_u, bk_m, E);
    k_bucket_scan<<<1, 256, 0, stream>>>(bk_u, bk_m, bkrp_u, bkrp_m, bcur_u, bcur_m, NBu, NBm, E);
    // movie CSR (key=dst, val=src), then user CSR (key=src, val=dst); pairs buffer reused
    k_bucket_scatter<<<sgrid, 256, 0, stream>>>(rates_dst, rates_src, bcur_m, pairs, E, NBm);
    k_bucket_finalize<<<NBm, 256, 0, stream>>>(pairs, bkrp_m, rp_m, nbr_m, NM, E);
    k_bucket_scatter<<<sgrid, 256, 0, stream>>>(rates_src, rates_dst, bcur_u, pairs, E, NBu);
    k_bucket_finalize<<<NBu, 256, 0, stream>>>(pairs, bkrp_u, rp_u, nbr_u, NU, E);

    // ---- init node features ----
    k_movie_feat<<<(NM + 255) / 256, 256, 0, stream>>>(movie_x, mlw, mlb, movie_emb, movie_node_id, xm_a, NM, F);
    k_gather_rows<<<2048, 256, 0, stream>>>(user_emb, user_node_id, xu_a, NU);

    // ---- stage 0: user <- rev(movie) ----
    k_reduce_mean<0><<<(NU + 7) / 8, 256, 0, stream>>>(xm_a, ss_id, rp_u, nbr_u, meanb, NU);
    k_sage_mfma<0><<<(NU + 63) / 64, 256, 0, stream>>>(meanb, xu_a, ss_id, wp0,
        (const float*)d_in[iL0RE + 1], xu_b, st0, NU);
    k_bn_finalize<<<1, 64, 0, stream>>>(st0, (const float*)d_in[iBN0U], (const float*)d_in[iBN0U + 1], ss_u0, NU);
    // ---- stage 1: movie <- rates(user) ----
    k_reduce_mean<0><<<(NM + 7) / 8, 256, 0, stream>>>(xu_a, ss_id, rp_m, nbr_m, meanb, NM);
    k_sage_mfma<0><<<(NM + 63) / 64, 256, 0, stream>>>(meanb, xm_a, ss_id, wp1,
        (const float*)d_in[iL0RA + 1], xm_b, st1, NM);
    k_bn_finalize<<<1, 64, 0, stream>>>(st1, (const float*)d_in[iBN0M], (const float*)d_in[iBN0M + 1], ss_m0, NM);
    // ---- stage 2: user layer 1 ----
    k_reduce_mean<1><<<(NU + 7) / 8, 256, 0, stream>>>(xm_b, ss_m0, rp_u, nbr_u, meanb, NU);
    k_sage_mfma<1><<<(NU + 63) / 64, 256, 0, stream>>>(meanb, xu_b, ss_u0, wp2,
        (const float*)d_in[iL1RE + 1], xu_a, st2, NU);
    k_bn_finalize<<<1, 64, 0, stream>>>(st2, (const float*)d_in[iBN1U], (const float*)d_in[iBN1U + 1], ss_u1, NU);
    // ---- stage 3: movie layer 1 ----
    k_reduce_mean<1><<<(NM + 7) / 8, 256, 0, stream>>>(xu_b, ss_u0, rp_m, nbr_m, meanb, NM);
    k_sage_mfma<1><<<(NM + 63) / 64, 256, 0, stream>>>(meanb, xm_b, ss_m0, wp3,
        (const float*)d_in[iL1RA + 1], xm_a, st3, NM);
    k_bn_finalize<<<1, 64, 0, stream>>>(st3, (const float*)d_in[iBN1M], (const float*)d_in[iBN1M + 1], ss_m1, NM);

    // ---- classifier ----
    k_cls_mfma<<<(L + 63) / 64, 256, 0, stream>>>(xu_a, ss_u1, xm_a, ss_m1,
        label_src, label_dst, wpc, cls_b1, cls_w2, cls_b2, (float*)d_out, L);
}

// Round 6
// 331.919 us; speedup vs baseline: 5.6452x; 1.2560x over previous
//
#include <hip/hip_runtime.h>
#include <hip/hip_bf16.h>
#include <stdint.h>

#define HD 64
#define CHUNK 4096
#define EPT 16
#define BSHIFT 9
#define BSIZE 512
#define FCAP 12288
#define VMASK 0x7fffffu   // low 23 bits = value; high 9 bits = node-within-bucket
#define NREP 64           // stats replicas (contention spreading)

typedef __bf16 bf16x8 __attribute__((ext_vector_type(8)));
typedef float f32x4 __attribute__((ext_vector_type(4)));

__device__ __forceinline__ void atomAddF(float* p, float v) { unsafeAtomicAdd(p, v); }
__device__ __forceinline__ ushort f2bf(float v) {
    __hip_bfloat16 h = __float2bfloat16(v);
    return *(ushort*)&h;
}
__device__ __forceinline__ float bf2f(ushort u) {
    return __uint_as_float(((uint)u) << 16);
}
__device__ __forceinline__ uint pack2(float a, float b) {
    return (uint)f2bf(a) | ((uint)f2bf(b) << 16);
}

// ---------------- CSR build (bucket-local) ----------------

__global__ __launch_bounds__(256) void k_bucket_hist(
    const int* __restrict__ src, const int* __restrict__ dst,
    int* __restrict__ bk_u, int* __restrict__ bk_m, int E)
{
    __shared__ int hu[256], hm[256];
    int tid = threadIdx.x;
    hu[tid] = 0; hm[tid] = 0;
    __syncthreads();
    int t = blockIdx.x * 256 + tid;
    int stride = gridDim.x * 256;
    for (; t < E; t += stride) {
        atomicAdd(&hu[src[t] >> BSHIFT], 1);
        atomicAdd(&hm[dst[t] >> BSHIFT], 1);
    }
    __syncthreads();
    if (hu[tid]) atomicAdd(&bk_u[tid], hu[tid]);
    if (hm[tid]) atomicAdd(&bk_m[tid], hm[tid]);
}

__global__ void k_bucket_scan(const int* __restrict__ bk_u, const int* __restrict__ bk_m,
                              int* __restrict__ bkrp_u, int* __restrict__ bkrp_m,
                              int* __restrict__ bcur_u, int* __restrict__ bcur_m,
                              int NBu, int NBm, int E)
{
    __shared__ int sh[256];
    int t = threadIdx.x;
    int v = (t < NBu) ? bk_u[t] : 0;
    sh[t] = v; __syncthreads();
    for (int off = 1; off < 256; off <<= 1) {
        int x = (t >= off) ? sh[t - off] : 0;
        __syncthreads(); sh[t] += x; __syncthreads();
    }
    int excl = sh[t] - v;
    if (t < NBu) { bkrp_u[t] = excl; bcur_u[t] = excl; }
    if (t == NBu) bkrp_u[t] = E;
    __syncthreads();
    v = (t < NBm) ? bk_m[t] : 0;
    sh[t] = v; __syncthreads();
    for (int off = 1; off < 256; off <<= 1) {
        int x = (t >= off) ? sh[t - off] : 0;
        __syncthreads(); sh[t] += x; __syncthreads();
    }
    excl = sh[t] - v;
    if (t < NBm) { bkrp_m[t] = excl; bcur_m[t] = excl; }
    if (t == NBm) bkrp_m[t] = E;
}

__global__ __launch_bounds__(256) void k_bucket_scatter(
    const int* __restrict__ key, const int* __restrict__ val,
    int* __restrict__ bcur, uint* __restrict__ pairs, int E, int NB)
{
    __shared__ int lcnt[256], lstart[256], gbase[256];
    __shared__ uint2 lpair[CHUNK];
    int tid = threadIdx.x;
    int base = blockIdx.x * CHUNK;
    int kk[EPT], vv[EPT], ofs[EPT];
    #pragma unroll
    for (int i = 0; i < EPT; ++i) {
        int idx = base + i * 256 + tid;
        bool ok = idx < E;
        kk[i] = ok ? key[idx] : -1;
        vv[i] = ok ? val[idx] : 0;
    }
    lcnt[tid] = 0;
    __syncthreads();
    #pragma unroll
    for (int i = 0; i < EPT; ++i)
        if (kk[i] >= 0) ofs[i] = atomicAdd(&lcnt[kk[i] >> BSHIFT], 1);
    __syncthreads();
    int c = lcnt[tid];
    lstart[tid] = c;
    __syncthreads();
    for (int off = 1; off < 256; off <<= 1) {
        int x = (tid >= off) ? lstart[tid - off] : 0;
        __syncthreads(); lstart[tid] += x; __syncthreads();
    }
    lstart[tid] -= c;
    if (c > 0 && tid < NB) gbase[tid] = atomicAdd(&bcur[tid], c);
    __syncthreads();
    #pragma unroll
    for (int i = 0; i < EPT; ++i)
        if (kk[i] >= 0) {
            int b = kk[i] >> BSHIFT;
            lpair[lstart[b] + ofs[i]] = make_uint2((uint)kk[i], (uint)vv[i]);
        }
    __syncthreads();
    int total = E - base; if (total > CHUNK) total = CHUNK;
    for (int j = tid; j < total; j += 256) {
        uint2 p = lpair[j];
        int b = (int)(p.x >> BSHIFT);
        pairs[gbase[b] + (j - lstart[b])] = ((p.x & (BSIZE - 1)) << 23) | p.y;
    }
}

__global__ __launch_bounds__(256) void k_bucket_finalize(
    const uint* __restrict__ pairs, const int* __restrict__ bkrp,
    int* __restrict__ rp, int* __restrict__ nbr, int N, int E)
{
    __shared__ int lcnt[BSIZE];
    __shared__ int lsc[256];
    __shared__ uint lp[FCAP];
    int b = blockIdx.x, tid = threadIdx.x;
    int base = b << BSHIFT;
    int rs = bkrp[b], re = bkrp[b + 1];
    int cnt = re - rs;
    bool staged = cnt <= FCAP;
    lcnt[tid] = 0; lcnt[tid + 256] = 0;
    __syncthreads();
    if (staged) {
        for (int j = tid; j < cnt; j += 256) {
            uint p = pairs[rs + j];
            lp[j] = p;
            atomicAdd(&lcnt[p >> 23], 1);
        }
    } else {
        for (int j = rs + tid; j < re; j += 256)
            atomicAdd(&lcnt[pairs[j] >> 23], 1);
    }
    __syncthreads();
    int c0 = lcnt[2 * tid], c1 = lcnt[2 * tid + 1];
    int s = c0 + c1;
    lsc[tid] = s;
    __syncthreads();
    for (int off = 1; off < 256; off <<= 1) {
        int x = (tid >= off) ? lsc[tid - off] : 0;
        __syncthreads(); lsc[tid] += x; __syncthreads();
    }
    int excl = lsc[tid] - s;
    int nbn = N - base; if (nbn > BSIZE) nbn = BSIZE;
    if (2 * tid < nbn)     rp[base + 2 * tid]     = rs + excl;
    if (2 * tid + 1 < nbn) rp[base + 2 * tid + 1] = rs + excl + c0;
    if (b == gridDim.x - 1 && tid == 0) rp[N] = E;
    lcnt[2 * tid] = excl;
    lcnt[2 * tid + 1] = excl + c0;
    __syncthreads();
    if (staged) {
        for (int j = tid; j < cnt; j += 256) {
            uint p = lp[j];
            int pos = rs + atomicAdd(&lcnt[p >> 23], 1);
            nbr[pos] = (int)(p & VMASK);
        }
    } else {
        for (int j = rs + tid; j < re; j += 256) {
            uint p = pairs[j];
            int pos = rs + atomicAdd(&lcnt[p >> 23], 1);
            nbr[pos] = (int)(p & VMASK);
        }
    }
}

// ---------------- weight fragment packing (5 matrices, one kernel) ----------------
__global__ void k_pack_all(const float* __restrict__ w0lo, const float* __restrict__ w0hi,
                           const float* __restrict__ w1lo, const float* __restrict__ w1hi,
                           const float* __restrict__ w2lo, const float* __restrict__ w2hi,
                           const float* __restrict__ w3lo, const float* __restrict__ w3hi,
                           const float* __restrict__ w4lo, const float* __restrict__ w4hi,
                           ushort* __restrict__ dst) {
    int t = blockIdx.x * blockDim.x + threadIdx.x;   // 40960 threads
    int mid = t >> 13, r = t & 8191;
    const float* lo; const float* hi;
    switch (mid) {
        case 0: lo = w0lo; hi = w0hi; break;
        case 1: lo = w1lo; hi = w1hi; break;
        case 2: lo = w2lo; hi = w2hi; break;
        case 3: lo = w3lo; hi = w3hi; break;
        default: lo = w4lo; hi = w4hi;
    }
    int e = r & 7, lane = (r >> 3) & 63, nn = (r >> 9) & 3, kk = r >> 11;
    int k = (lane >> 4) * 8 + e + 32 * kk;
    int col = (lane & 15) + 16 * nn;
    float v = (k < 64) ? lo[k * 64 + col] : hi[(k - 64) * 64 + col];
    dst[t] = f2bf(v);
}

__global__ void k_init_ss(float* __restrict__ ss_id) {
    int t = threadIdx.x;
    if (t < 64) { ss_id[t] = 1.f; ss_id[64 + t] = 0.f; }
}

// ---------------- segmented mean (half-wave per node, uint loads, fused BN) ----------------
template<int RELU>
__global__ __launch_bounds__(256) void k_reduce_mean(
    const ushort* __restrict__ xsrc, const float* __restrict__ ssx,
    const int* __restrict__ rp, const int* __restrict__ nbr,
    ushort* __restrict__ mean, int N)
{
    int slot = blockIdx.x * 8 + (threadIdx.x >> 5);
    if (slot >= N) return;
    int c = threadIdx.x & 31;
    float sc0 = ssx[2 * c], sc1 = ssx[2 * c + 1];
    float sh0 = ssx[64 + 2 * c], sh1 = ssx[64 + 2 * c + 1];
    const uint* xs = (const uint*)xsrc;
    int s0 = rp[slot], s1 = rp[slot + 1];
    float a0 = 0.f, a1 = 0.f;
    int k = s0;
    for (; k + 4 <= s1; k += 4) {
        int n0 = nbr[k], n1 = nbr[k + 1], n2 = nbr[k + 2], n3 = nbr[k + 3];
        uint u0 = xs[(size_t)n0 * 32 + c], u1 = xs[(size_t)n1 * 32 + c];
        uint u2 = xs[(size_t)n2 * 32 + c], u3 = xs[(size_t)n3 * 32 + c];
        uint uu[4] = {u0, u1, u2, u3};
        #pragma unroll
        for (int i = 0; i < 4; ++i) {
            float f0 = __uint_as_float(uu[i] << 16) * sc0 + sh0;
            float f1 = __uint_as_float(uu[i] & 0xffff0000u) * sc1 + sh1;
            if (RELU) { f0 = fmaxf(f0, 0.f); f1 = fmaxf(f1, 0.f); }
            a0 += f0; a1 += f1;
        }
    }
    for (; k < s1; ++k) {
        uint u = xs[(size_t)nbr[k] * 32 + c];
        float f0 = __uint_as_float(u << 16) * sc0 + sh0;
        float f1 = __uint_as_float(u & 0xffff0000u) * sc1 + sh1;
        if (RELU) { f0 = fmaxf(f0, 0.f); f1 = fmaxf(f1, 0.f); }
        a0 += f0; a1 += f1;
    }
    float inv = (s1 > s0) ? 1.f / (float)(s1 - s0) : 0.f;
    ((uint*)mean)[(size_t)slot * 32 + c] = pack2(a0 * inv, a1 * inv);
}

// BN-apply on a bf16x8 A-fragment (sc/sh point at the 8-col window)
template<int RELU>
__device__ __forceinline__ bf16x8 bn_frag(bf16x8 raw, const float* sc, const float* sh) {
    bf16x8 o;
    #pragma unroll
    for (int e = 0; e < 8; ++e) {
        float f = bf2f(((const ushort*)&raw)[e]);
        f = f * sc[e] + sh[e];
        if (RELU) f = fmaxf(f, 0.f);
        ((ushort*)&o)[e] = f2bf(f);
    }
    return o;
}

// ---------------- MFMA: out = [mean | BN(xdst)] @ Wcat + bias, fused col-stats ----------------
// stats: NREP replicas of 128 floats; block writes replica (blockIdx & (NREP-1))
template<int RELU>
__global__ __launch_bounds__(256) void k_sage_mfma(
    const ushort* __restrict__ meanb, const ushort* __restrict__ xdst,
    const float* __restrict__ ssd,
    const ushort* __restrict__ wp, const float* __restrict__ blv,
    ushort* __restrict__ out, float* __restrict__ stats, int N)
{
    __shared__ float lsum[64], lsq[64];
    if (threadIdx.x < 64) { lsum[threadIdx.x] = 0.f; lsq[threadIdx.x] = 0.f; }
    __syncthreads();
    int wave = threadIdx.x >> 6, lane = threadIdx.x & 63;
    int n0 = blockIdx.x * 64 + wave * 16;
    int lrow = lane & 15, lk = lane >> 4;
    int arow = n0 + lrow; if (arow >= N) arow = N - 1;
    const ushort* pm = meanb + (size_t)arow * HD + lk * 8;
    const ushort* px = xdst  + (size_t)arow * HD + lk * 8;
    const bf16x8* wpv = (const bf16x8*)wp + lane;

    bf16x8 b[4][4];
    #pragma unroll
    for (int kk = 0; kk < 4; ++kk)
        #pragma unroll
        for (int nn = 0; nn < 4; ++nn)
            b[kk][nn] = wpv[(kk * 4 + nn) * 64];

    bf16x8 a[4];
    a[0] = *(const bf16x8*)(pm);
    a[1] = *(const bf16x8*)(pm + 32);
    a[2] = bn_frag<RELU>(*(const bf16x8*)(px),      ssd + lk * 8,      ssd + 64 + lk * 8);
    a[3] = bn_frag<RELU>(*(const bf16x8*)(px + 32), ssd + 32 + lk * 8, ssd + 96 + lk * 8);

    f32x4 acc[4];
    #pragma unroll
    for (int nn = 0; nn < 4; ++nn) acc[nn] = (f32x4){0.f, 0.f, 0.f, 0.f};
    #pragma unroll
    for (int kk = 0; kk < 4; ++kk)
        #pragma unroll
        for (int nn = 0; nn < 4; ++nn)
            acc[nn] = __builtin_amdgcn_mfma_f32_16x16x32_bf16(a[kk], b[kk][nn], acc[nn], 0, 0, 0);

    #pragma unroll
    for (int nn = 0; nn < 4; ++nn) {
        float bias = blv[lrow + 16 * nn];
        float s = 0.f, q = 0.f;
        #pragma unroll
        for (int r = 0; r < 4; ++r) {
            int orow = n0 + lk * 4 + r;
            float v = acc[nn][r] + bias;
            bool ok = orow < N;
            if (ok) out[(size_t)orow * HD + lrow + 16 * nn] = f2bf(v);
            float vv = ok ? v : 0.f;
            s += vv; q += vv * vv;
        }
        s += __shfl_xor(s, 16); s += __shfl_xor(s, 32);
        q += __shfl_xor(q, 16); q += __shfl_xor(q, 32);
        if (lk == 0) {
            atomAddF(&lsum[lrow + 16 * nn], s);
            atomAddF(&lsq[lrow + 16 * nn], q);
        }
    }
    __syncthreads();
    float* st = stats + (size_t)(blockIdx.x & (NREP - 1)) * 128;
    if (threadIdx.x < 64) {
        atomAddF(&st[threadIdx.x], lsum[threadIdx.x]);
        atomAddF(&st[64 + threadIdx.x], lsq[threadIdx.x]);
    }
}

// reduce NREP stat replicas, then compute scale/shift. 128 threads, 1 block.
__global__ void k_bn_finalize(const float* __restrict__ stats,
                              const float* __restrict__ g, const float* __restrict__ b,
                              float* __restrict__ ss, int N)
{
    __shared__ float red[128];
    int j = threadIdx.x;   // 0..127
    float s = 0.f;
    #pragma unroll 8
    for (int r = 0; r < NREP; ++r) s += stats[r * 128 + j];
    red[j] = s;
    __syncthreads();
    if (j < HD) {
        float invN = 1.f / (float)N;
        float mu = red[j] * invN;
        float var = red[HD + j] * invN - mu * mu;
        var = var < 0.f ? 0.f : var;
        float sc = g[j] * rsqrtf(var + 1e-5f);
        ss[j] = sc;
        ss[HD + j] = b[j] - mu * sc;
    }
}

// ---------------- classifier (BN both operands, fused) ----------------
__global__ __launch_bounds__(256) void k_cls_mfma(
    const ushort* __restrict__ xu, const float* __restrict__ ssu,
    const ushort* __restrict__ xm, const float* __restrict__ ssm,
    const int* __restrict__ lsrc, const int* __restrict__ ldst,
    const ushort* __restrict__ wp, const float* __restrict__ b1,
    const float* __restrict__ w2, const float* __restrict__ b2,
    float* __restrict__ out, int L)
{
    int wave = threadIdx.x >> 6, lane = threadIdx.x & 63;
    int l0 = blockIdx.x * 64 + wave * 16;
    if (l0 >= L) return;
    int lrow = lane & 15, lk = lane >> 4;
    int li = l0 + lrow; if (li >= L) li = L - 1;
    const ushort* pu = xu + (size_t)lsrc[li] * HD + lk * 8;
    const ushort* pm = xm + (size_t)ldst[li] * HD + lk * 8;
    const bf16x8* wpv = (const bf16x8*)wp + lane;

    bf16x8 a[4];
    a[0] = bn_frag<1>(*(const bf16x8*)(pu),      ssu + lk * 8,      ssu + 64 + lk * 8);
    a[1] = bn_frag<1>(*(const bf16x8*)(pu + 32), ssu + 32 + lk * 8, ssu + 96 + lk * 8);
    a[2] = bn_frag<1>(*(const bf16x8*)(pm),      ssm + lk * 8,      ssm + 64 + lk * 8);
    a[3] = bn_frag<1>(*(const bf16x8*)(pm + 32), ssm + 32 + lk * 8, ssm + 96 + lk * 8);

    f32x4 acc[4];
    #pragma unroll
    for (int nn = 0; nn < 4; ++nn) acc[nn] = (f32x4){0.f, 0.f, 0.f, 0.f};
    #pragma unroll
    for (int kk = 0; kk < 4; ++kk)
        #pragma unroll
        for (int nn = 0; nn < 4; ++nn)
            acc[nn] = __builtin_amdgcn_mfma_f32_16x16x32_bf16(a[kk], wpv[(kk * 4 + nn) * 64], acc[nn], 0, 0, 0);

    float p0 = 0.f, p1 = 0.f, p2 = 0.f, p3 = 0.f;
    #pragma unroll
    for (int nn = 0; nn < 4; ++nn) {
        int cidx = lrow + 16 * nn;
        float bb = b1[cidx], w = w2[cidx];
        p0 += fmaxf(acc[nn][0] + bb, 0.f) * w;
        p1 += fmaxf(acc[nn][1] + bb, 0.f) * w;
        p2 += fmaxf(acc[nn][2] + bb, 0.f) * w;
        p3 += fmaxf(acc[nn][3] + bb, 0.f) * w;
    }
    #pragma unroll
    for (int off = 1; off < 16; off <<= 1) {
        p0 += __shfl_xor(p0, off);
        p1 += __shfl_xor(p1, off);
        p2 += __shfl_xor(p2, off);
        p3 += __shfl_xor(p3, off);
    }
    if (lrow == 0) {
        float bb2 = b2[0];
        int r0 = l0 + lk * 4;
        if (r0 + 0 < L) out[r0 + 0] = p0 + bb2;
        if (r0 + 1 < L) out[r0 + 1] = p1 + bb2;
        if (r0 + 2 < L) out[r0 + 2] = p2 + bb2;
        if (r0 + 3 < L) out[r0 + 3] = p3 + bb2;
    }
}

// ---------------- dense init ----------------

__global__ __launch_bounds__(256) void k_movie_feat(
    const float* __restrict__ mx, const float* __restrict__ W,
    const float* __restrict__ b, const float* __restrict__ memb,
    const int* __restrict__ mids, ushort* __restrict__ xm, int NM, int F)
{
    int m = blockIdx.x * blockDim.x + threadIdx.x;
    if (m >= NM) return;
    const float* xr = mx + (size_t)m * F;
    float acc[HD];
    #pragma unroll
    for (int j = 0; j < HD; ++j) acc[j] = b[j];
    for (int f = 0; f < F; ++f) {
        float v = xr[f];
        #pragma unroll
        for (int j = 0; j < HD; ++j) acc[j] += v * W[f * HD + j];
    }
    int nid = mids[m];
    const float* er = memb + (size_t)nid * HD;
    uint* o = (uint*)(xm + (size_t)m * HD);
    #pragma unroll
    for (int j = 0; j < HD; j += 2)
        o[j >> 1] = pack2(acc[j] + er[j], acc[j + 1] + er[j + 1]);
}

__global__ __launch_bounds__(256) void k_gather_rows(
    const float* __restrict__ src, const int* __restrict__ idx,
    ushort* __restrict__ dst, int N)
{
    int t = blockIdx.x * blockDim.x + threadIdx.x;
    int total = N * HD;
    int stride = gridDim.x * blockDim.x;
    for (; t < total; t += stride) {
        int i = t >> 6, h = t & 63;
        dst[t] = f2bf(src[(size_t)idx[i] * HD + h]);
    }
}

extern "C" void kernel_launch(void* const* d_in, const int* in_sizes, int n_in,
                              void* d_out, int out_size, void* d_ws, size_t ws_size,
                              hipStream_t stream) {
    (void)n_in; (void)ws_size;
    const int NU = in_sizes[1] / HD;
    const int NM = in_sizes[2] / HD;
    const int F  = in_sizes[0] / NM;
    const int E  = in_sizes[31];
    const int L  = out_size;
    const int NBm = (NM + BSIZE - 1) >> BSHIFT;
    const int NBu = (NU + BSIZE - 1) >> BSHIFT;

    int iL0RA, iL0RE, iL1RA, iL1RE, iBN0U, iBN0M, iBN1U, iBN1M;
    if (in_sizes[11] == HD) {          // setup-dict order
        iL0RA = 5; iL0RE = 8; iBN0U = 11; iBN0M = 13;
        iL1RA = 15; iL1RE = 18; iBN1U = 21; iBN1M = 23;
    } else {                           // reference-signature order
        iL0RA = 5; iL0RE = 8; iL1RA = 11; iL1RE = 14;
        iBN0U = 17; iBN0M = 19; iBN1U = 21; iBN1M = 23;
    }
    const float* movie_x   = (const float*)d_in[0];
    const float* user_emb  = (const float*)d_in[1];
    const float* movie_emb = (const float*)d_in[2];
    const float* mlw       = (const float*)d_in[3];
    const float* mlb       = (const float*)d_in[4];
    const float* cls_w1    = (const float*)d_in[25];
    const float* cls_b1    = (const float*)d_in[26];
    const float* cls_w2    = (const float*)d_in[27];
    const float* cls_b2    = (const float*)d_in[28];
    const int* user_node_id  = (const int*)d_in[29];
    const int* movie_node_id = (const int*)d_in[30];
    const int* rates_src   = (const int*)d_in[31];
    const int* rates_dst   = (const int*)d_in[32];
    const int* label_src   = (const int*)d_in[33];
    const int* label_dst   = (const int*)d_in[34];

    // ---- workspace ----
    char* wsb = (char*)d_ws;
    auto alloc = [&](size_t bytes) { char* p = wsb; wsb += (bytes + 255) & ~(size_t)255; return p; };
    int nmax = NU > NM ? NU : NM;
    ushort* xu_a = (ushort*)alloc((size_t)NU * HD * 2);
    ushort* xu_b = (ushort*)alloc((size_t)NU * HD * 2);
    ushort* xm_a = (ushort*)alloc((size_t)NM * HD * 2);
    ushort* xm_b = (ushort*)alloc((size_t)NM * HD * 2);
    ushort* meanb = (ushort*)alloc((size_t)nmax * HD * 2);
    ushort* wp_all = (ushort*)alloc(5 * 8192 * 2);
    int* rp_m = (int*)alloc((size_t)(NM + 1) * 4);
    int* rp_u = (int*)alloc((size_t)(NU + 1) * 4);
    int* nbr_m = (int*)alloc((size_t)E * 4);
    int* nbr_u = (int*)alloc((size_t)E * 4);
    uint* pairs = (uint*)alloc((size_t)E * 4);
    int* bkrp_m = (int*)alloc(257 * 4);
    int* bkrp_u = (int*)alloc(257 * 4);
    int* bcur_m = (int*)alloc(256 * 4);
    int* bcur_u = (int*)alloc(256 * 4);
    // zeroed region: bucket counts + 4 stages x NREP x 128 stats
    size_t zr_bytes = 2 * 256 * 4 + (size_t)4 * NREP * 128 * 4;
    char* zr = alloc(zr_bytes);
    int* bk_u = (int*)zr;
    int* bk_m = bk_u + 256;
    float* statsAll = (float*)(bk_m + 256);
    float* ss_id = (float*)alloc(128 * 4);
    float* ss_u0 = (float*)alloc(128 * 4);
    float* ss_m0 = (float*)alloc(128 * 4);
    float* ss_u1 = (float*)alloc(128 * 4);
    float* ss_m1 = (float*)alloc(128 * 4);

    ushort* wp0 = wp_all;              // l0 rev
    ushort* wp1 = wp_all + 8192;       // l0 rates
    ushort* wp2 = wp_all + 16384;      // l1 rev
    ushort* wp3 = wp_all + 24576;      // l1 rates
    ushort* wpc = wp_all + 32768;      // classifier
    float* st0 = statsAll;
    float* st1 = statsAll + NREP * 128;
    float* st2 = statsAll + 2 * NREP * 128;
    float* st3 = statsAll + 3 * NREP * 128;

    const int sgrid = (E + CHUNK - 1) / CHUNK;

    hipMemsetAsync(zr, 0, zr_bytes, stream);
    k_init_ss<<<1, 64, 0, stream>>>(ss_id);
    k_pack_all<<<160, 256, 0, stream>>>(
        (const float*)d_in[iL0RE + 0], (const float*)d_in[iL0RE + 2],
        (const float*)d_in[iL0RA + 0], (const float*)d_in[iL0RA + 2],
        (const float*)d_in[iL1RE + 0], (const float*)d_in[iL1RE + 2],
        (const float*)d_in[iL1RA + 0], (const float*)d_in[iL1RA + 2],
        cls_w1, cls_w1 + 64 * 64, wp_all);

    // ---- CSR build (bucket-local) ----
    k_bucket_hist<<<1024, 256, 0, stream>>>(rates_src, rates_dst, bk_u, bk_m, E);
    k_bucket_scan<<<1, 256, 0, stream>>>(bk_u, bk_m, bkrp_u, bkrp_m, bcur_u, bcur_m, NBu, NBm, E);
    k_bucket_scatter<<<sgrid, 256, 0, stream>>>(rates_dst, rates_src, bcur_m, pairs, E, NBm);
    k_bucket_finalize<<<NBm, 256, 0, stream>>>(pairs, bkrp_m, rp_m, nbr_m, NM, E);
    k_bucket_scatter<<<sgrid, 256, 0, stream>>>(rates_src, rates_dst, bcur_u, pairs, E, NBu);
    k_bucket_finalize<<<NBu, 256, 0, stream>>>(pairs, bkrp_u, rp_u, nbr_u, NU, E);

    // ---- init node features ----
    k_movie_feat<<<(NM + 255) / 256, 256, 0, stream>>>(movie_x, mlw, mlb, movie_emb, movie_node_id, xm_a, NM, F);
    k_gather_rows<<<2048, 256, 0, stream>>>(user_emb, user_node_id, xu_a, NU);

    // ---- stage 0: user <- rev(movie) ----
    k_reduce_mean<0><<<(NU + 7) / 8, 256, 0, stream>>>(xm_a, ss_id, rp_u, nbr_u, meanb, NU);
    k_sage_mfma<0><<<(NU + 63) / 64, 256, 0, stream>>>(meanb, xu_a, ss_id, wp0,
        (const float*)d_in[iL0RE + 1], xu_b, st0, NU);
    k_bn_finalize<<<1, 128, 0, stream>>>(st0, (const float*)d_in[iBN0U], (const float*)d_in[iBN0U + 1], ss_u0, NU);
    // ---- stage 1: movie <- rates(user) ----
    k_reduce_mean<0><<<(NM + 7) / 8, 256, 0, stream>>>(xu_a, ss_id, rp_m, nbr_m, meanb, NM);
    k_sage_mfma<0><<<(NM + 63) / 64, 256, 0, stream>>>(meanb, xm_a, ss_id, wp1,
        (const float*)d_in[iL0RA + 1], xm_b, st1, NM);
    k_bn_finalize<<<1, 128, 0, stream>>>(st1, (const float*)d_in[iBN0M], (const float*)d_in[iBN0M + 1], ss_m0, NM);
    // ---- stage 2: user layer 1 ----
    k_reduce_mean<1><<<(NU + 7) / 8, 256, 0, stream>>>(xm_b, ss_m0, rp_u, nbr_u, meanb, NU);
    k_sage_mfma<1><<<(NU + 63) / 64, 256, 0, stream>>>(meanb, xu_b, ss_u0, wp2,
        (const float*)d_in[iL1RE + 1], xu_a, st2, NU);
    k_bn_finalize<<<1, 128, 0, stream>>>(st2, (const float*)d_in[iBN1U], (const float*)d_in[iBN1U + 1], ss_u1, NU);
    // ---- stage 3: movie layer 1 ----
    k_reduce_mean<1><<<(NM + 7) / 8, 256, 0, stream>>>(xu_b, ss_u0, rp_m, nbr_m, meanb, NM);
    k_sage_mfma<1><<<(NM + 63) / 64, 256, 0, stream>>>(meanb, xm_b, ss_m0, wp3,
        (const float*)d_in[iL1RA + 1], xm_a, st3, NM);
    k_bn_finalize<<<1, 128, 0, stream>>>(st3, (const float*)d_in[iBN1M], (const float*)d_in[iBN1M + 1], ss_m1, NM);

    // ---- classifier ----
    k_cls_mfma<<<(L + 63) / 64, 256, 0, stream>>>(xu_a, ss_u1, xm_a, ss_m1,
        label_src, label_dst, wpc, cls_b1, cls_w2, cls_b2, (float*)d_out, L);
}